// Round 3
// baseline (1007.925 us; speedup 1.0000x reference)
//
#include <hip/hip_runtime.h>

#define D 128
#define BN_EPS 1e-5f

typedef unsigned short u16;

__device__ __forceinline__ float bf2f(u16 u) {
    unsigned v = (unsigned)u << 16; float f; __builtin_memcpy(&f, &v, 4); return f;
}
__device__ __forceinline__ u16 f2bf(float f) {
    unsigned v; __builtin_memcpy(&v, &f, 4);
    v += 0x7FFFu + ((v >> 16) & 1u);          // round-to-nearest-even
    return (u16)(v >> 16);
}

// ---------------- utility: zero an int/float buffer ----------------
__global__ __launch_bounds__(256) void k_zero(int* __restrict__ p, int n)
{
    int i = blockIdx.x * 256 + threadIdx.x;
    if (i < n) p[i] = 0;
}

// ---------------- preprocessing: degrees + CSR by dst ----------------
// NOTE: harness materializes integer inputs as int32 (reference int64 -> device int32).
__global__ __launch_bounds__(256) void k_deg(const int* __restrict__ ei, const float* __restrict__ ew,
                                             float* __restrict__ degw, int* __restrict__ cnt, int E)
{
    int e = blockIdx.x * 256 + threadIdx.x;
    if (e >= E) return;
    int d = ei[(size_t)E + e];
    atomicAdd(&degw[d], ew[e]);
    atomicAdd(&cnt[d], 1);
}

__global__ __launch_bounds__(256) void k_dinv(float* __restrict__ degw, int N)
{
    int i = blockIdx.x * 256 + threadIdx.x;
    if (i < N) degw[i] = rsqrtf(degw[i] + 1.0f);   // +1 = self-loop weight; deg >= 1 always
}

// single-block scan: exclusive prefix over cnt[0..N-1] -> rowptr[0..N]
__global__ __launch_bounds__(1024) void k_scan(const int* __restrict__ cnt, int* __restrict__ rowptr, int N)
{
    __shared__ int wsum[17];
    __shared__ int carry_s;
    int tid = threadIdx.x, lane = tid & 63, wid = tid >> 6;
    if (tid == 0) carry_s = 0;
    __syncthreads();
    for (int base = 0; base < N; base += 8192) {
        int i0 = base + tid * 8;
        int v[8], s[8];
        int run = 0;
#pragma unroll
        for (int j = 0; j < 8; ++j) {
            int i = i0 + j;
            v[j] = (i < N) ? cnt[i] : 0;
            run += v[j];
            s[j] = run;
        }
        int inc = run;
#pragma unroll
        for (int off = 1; off < 64; off <<= 1) {
            int t = __shfl_up(inc, (unsigned)off, 64);
            if (lane >= off) inc += t;
        }
        if (lane == 63) wsum[wid] = inc;
        __syncthreads();
        if (wid == 0) {
            int w = (lane < 16) ? wsum[lane] : 0;
            int winc = w;
#pragma unroll
            for (int off = 1; off < 16; off <<= 1) {
                int t = __shfl_up(winc, (unsigned)off, 64);
                if (lane >= off) winc += t;
            }
            if (lane < 16) wsum[lane] = winc - w;   // exclusive wave offset
            if (lane == 15) wsum[16] = winc;        // tile total
        }
        __syncthreads();
        int toff = carry_s + wsum[wid] + (inc - run);
#pragma unroll
        for (int j = 0; j < 8; ++j) {
            int i = i0 + j;
            if (i < N) rowptr[i] = toff + s[j] - v[j];
        }
        __syncthreads();
        if (tid == 0) carry_s += wsum[16];
        __syncthreads();
    }
    if (threadIdx.x == 0) rowptr[N] = carry_s;
}

__global__ __launch_bounds__(256) void k_fill(const int* __restrict__ ei, const float* __restrict__ ew,
                                              const float* __restrict__ dinv, const int* __restrict__ rowptr,
                                              int* __restrict__ fillc, int* __restrict__ col,
                                              float* __restrict__ val, int E)
{
    int e = blockIdx.x * 256 + threadIdx.x;
    if (e >= E) return;
    int s = ei[e];
    int d = ei[(size_t)E + e];
    float nrm = dinv[s] * ew[e] * dinv[d];
    int p = rowptr[d] + atomicAdd(&fillc[d], 1);
    col[p] = s;
    val[p] = nrm;
}

// ---------------- GEMM: H[N,128] = X[N,128] @ W[128,128], H stored bf16 ----------------
__global__ __launch_bounds__(256) void k_gemm(const float* __restrict__ X, const float* __restrict__ W,
                                              u16* __restrict__ H, int N)
{
    __shared__ float lw[D * 64];
    int lane = threadIdx.x & 63;
    int rowbase = blockIdx.x * 64 + (threadIdx.x >> 6) * 16;
    for (int h = 0; h < 2; ++h) {
        __syncthreads();
        for (int i = threadIdx.x; i < D * 64; i += 256) {
            int k = i >> 6, c = i & 63;
            lw[i] = W[k * D + h * 64 + c];
        }
        __syncthreads();
        for (int p = 0; p < 4; ++p) {
            int r0 = rowbase + p * 4;
            int c0 = r0 + 0 < N ? r0 + 0 : 0;
            int c1 = r0 + 1 < N ? r0 + 1 : 0;
            int c2 = r0 + 2 < N ? r0 + 2 : 0;
            int c3 = r0 + 3 < N ? r0 + 3 : 0;
            const float* x0 = X + (size_t)__builtin_amdgcn_readfirstlane(c0) * D;
            const float* x1 = X + (size_t)__builtin_amdgcn_readfirstlane(c1) * D;
            const float* x2 = X + (size_t)__builtin_amdgcn_readfirstlane(c2) * D;
            const float* x3 = X + (size_t)__builtin_amdgcn_readfirstlane(c3) * D;
            float a0 = 0.f, a1 = 0.f, a2 = 0.f, a3 = 0.f;
#pragma unroll 16
            for (int k = 0; k < D; ++k) {
                float w = lw[k * 64 + lane];
                a0 = fmaf(x0[k], w, a0);
                a1 = fmaf(x1[k], w, a1);
                a2 = fmaf(x2[k], w, a2);
                a3 = fmaf(x3[k], w, a3);
            }
            if (r0 + 0 < N) H[(size_t)(r0 + 0) * D + h * 64 + lane] = f2bf(a0);
            if (r0 + 1 < N) H[(size_t)(r0 + 1) * D + h * 64 + lane] = f2bf(a1);
            if (r0 + 2 < N) H[(size_t)(r0 + 2) * D + h * 64 + lane] = f2bf(a2);
            if (r0 + 3 < N) H[(size_t)(r0 + 3) * D + h * 64 + lane] = f2bf(a3);
        }
    }
}

// ---------------- aggregation: out[n] = sum_{e: dst=n} norm_e * h[src_e] + dinv[n]^2*h[n] + b ----
__global__ __launch_bounds__(256) void k_gather(const u16* __restrict__ h, const int* __restrict__ rowptr,
                                                const int* __restrict__ col, const float* __restrict__ val,
                                                const float* __restrict__ dinv, const float* __restrict__ bias,
                                                float* __restrict__ out, int N)
{
    int wid = blockIdx.x * 4 + (threadIdx.x >> 6);
    int lane = threadIdx.x & 63;
    if (wid >= N) return;
    float di = dinv[wid];
    float sw = di * di;                       // self-loop norm (ew = 1)
    ushort2 hv = ((const ushort2*)(h + (size_t)wid * D))[lane];
    float ax = bf2f(hv.x) * sw, ay = bf2f(hv.y) * sw;
    int j   = __builtin_amdgcn_readfirstlane(rowptr[wid]);
    int end = __builtin_amdgcn_readfirstlane(rowptr[wid + 1]);
    for (; j + 4 <= end; j += 4) {
        int s0 = col[j], s1 = col[j + 1], s2 = col[j + 2], s3 = col[j + 3];
        float w0 = val[j], w1 = val[j + 1], w2 = val[j + 2], w3 = val[j + 3];
        ushort2 v0 = ((const ushort2*)(h + (size_t)s0 * D))[lane];
        ushort2 v1 = ((const ushort2*)(h + (size_t)s1 * D))[lane];
        ushort2 v2 = ((const ushort2*)(h + (size_t)s2 * D))[lane];
        ushort2 v3 = ((const ushort2*)(h + (size_t)s3 * D))[lane];
        ax = fmaf(w0, bf2f(v0.x), ax); ay = fmaf(w0, bf2f(v0.y), ay);
        ax = fmaf(w1, bf2f(v1.x), ax); ay = fmaf(w1, bf2f(v1.y), ay);
        ax = fmaf(w2, bf2f(v2.x), ax); ay = fmaf(w2, bf2f(v2.y), ay);
        ax = fmaf(w3, bf2f(v3.x), ax); ay = fmaf(w3, bf2f(v3.y), ay);
    }
    for (; j < end; ++j) {
        int s0 = col[j]; float w0 = val[j];
        ushort2 v0 = ((const ushort2*)(h + (size_t)s0 * D))[lane];
        ax = fmaf(w0, bf2f(v0.x), ax); ay = fmaf(w0, bf2f(v0.y), ay);
    }
    float2 b = ((const float2*)bias)[lane];
    float2 o; o.x = ax + b.x; o.y = ay + b.y;
    ((float2*)(out + (size_t)wid * D))[lane] = o;
}

// ---------------- BatchNorm ----------------
__global__ __launch_bounds__(256) void k_bnstats(const float* __restrict__ x, float* __restrict__ sums,
                                                 float* __restrict__ sumsq, int N)
{
    int c = threadIdx.x & 127;
    int half = threadIdx.x >> 7;
    int stride = gridDim.x * 2;
    float s = 0.f, s2 = 0.f;
    for (int r = blockIdx.x * 2 + half; r < N; r += stride) {
        float v = x[(size_t)r * D + c];
        s += v; s2 = fmaf(v, v, s2);
    }
    __shared__ float ls[256], ls2[256];
    ls[threadIdx.x] = s; ls2[threadIdx.x] = s2;
    __syncthreads();
    if (half == 0) {
        s += ls[c + 128]; s2 += ls2[c + 128];
        atomicAdd(&sums[c], s);
        atomicAdd(&sumsq[c], s2);
    }
}

__global__ __launch_bounds__(256) void k_bnapply(const float* __restrict__ in, const float* __restrict__ sums,
                                                 const float* __restrict__ sumsq, const float* __restrict__ g,
                                                 const float* __restrict__ be, float* __restrict__ out,
                                                 int N, float invN, int relu)
{
    int idx = blockIdx.x * 256 + threadIdx.x;
    if (idx >= N * 32) return;
    int cc = idx & 31;
    float4 xv = ((const float4*)in)[idx];
    float4 sv = ((const float4*)sums)[cc];
    float4 qv = ((const float4*)sumsq)[cc];
    float4 gv = ((const float4*)g)[cc];
    float4 bv = ((const float4*)be)[cc];
    float4 o;
#define BN1(X, SS, QQ, GG, BB, OO)                                     \
    {                                                                  \
        float mu = SS * invN;                                          \
        float var = fmaxf(QQ * invN - mu * mu, 0.f);                   \
        float rs = rsqrtf(var + BN_EPS);                               \
        float y = (X - mu) * rs * GG + BB;                             \
        OO = relu ? fmaxf(y, 0.f) : y;                                 \
    }
    BN1(xv.x, sv.x, qv.x, gv.x, bv.x, o.x)
    BN1(xv.y, sv.y, qv.y, gv.y, bv.y, o.y)
    BN1(xv.z, sv.z, qv.z, gv.z, bv.z, o.z)
    BN1(xv.w, sv.w, qv.w, gv.w, bv.w, o.w)
#undef BN1
    ((float4*)out)[idx] = o;
}

// ---------------- launch ----------------
extern "C" void kernel_launch(void* const* d_in, const int* in_sizes, int n_in,
                              void* d_out, int out_size, void* d_ws, size_t ws_size,
                              hipStream_t stream)
{
    const float* x  = (const float*)d_in[0];
    const int*   ei = (const int*)d_in[1];      // int32 on device (harness converts int64)
    const float* ew = (const float*)d_in[2];
    const float* W1 = (const float*)d_in[4];
    const float* b1 = (const float*)d_in[5];
    const float* W2 = (const float*)d_in[6];
    const float* b2 = (const float*)d_in[7];
    const float* W3 = (const float*)d_in[8];
    const float* b3 = (const float*)d_in[9];
    const float* g1 = (const float*)d_in[10];
    const float* be1 = (const float*)d_in[11];
    const float* g2 = (const float*)d_in[12];
    const float* be2 = (const float*)d_in[13];
    const float* g3 = (const float*)d_in[14];
    const float* be3 = (const float*)d_in[15];

    int N = in_sizes[0] / D;
    int E = in_sizes[1] / 2;
    float* P = (float*)d_out;      // the ONLY big f32 buffer (activations, in-place BN)

    char* ws = (char*)d_ws;
    size_t off = 0;
    auto alloc = [&](size_t bytes) -> void* {
        void* p = ws + off;
        off = (off + bytes + 255) & ~(size_t)255;
        return p;
    };
    u16*   Hb    = (u16*)alloc((size_t)N * D * 2);      // bf16 GEMM output, 25.6 MB
    float* degw  = (float*)alloc((size_t)N * 4);        // becomes dinv after k_dinv
    int*   cnt   = (int*)alloc((size_t)N * 4);          // reused as fill counters
    int*   rowptr= (int*)alloc((size_t)(N + 1) * 4);
    int*   colA  = (int*)alloc((size_t)E * 4);
    float* valA  = (float*)alloc((size_t)E * 4);
    float* stats = (float*)alloc(1024);                 // sums[128] ++ sumsq[128]
    float* sums  = stats;
    float* sumsq = stats + 128;

    float invN = 1.0f / (float)N;
    int egrid = (E + 255) / 256;
    int ngrid = (N + 255) / 256;
    int ggrid = (N + 63) / 64;
    int agrid = (N + 3) / 4;
    int pgrid = (N * 32 + 255) / 256;

    // ---- CSR build (per call; deterministic work) ----
    k_zero<<<ngrid, 256, 0, stream>>>((int*)degw, N);
    k_zero<<<ngrid, 256, 0, stream>>>(cnt, N);
    k_deg<<<egrid, 256, 0, stream>>>(ei, ew, degw, cnt, E);
    k_dinv<<<ngrid, 256, 0, stream>>>(degw, N);
    k_scan<<<1, 1024, 0, stream>>>(cnt, rowptr, N);
    k_zero<<<ngrid, 256, 0, stream>>>(cnt, N);
    k_fill<<<egrid, 256, 0, stream>>>(ei, ew, degw, rowptr, cnt, colA, valA, E);

    // ---- layer 1: x -> Hb (gemm) -> P (agg) -> stats -> P in-place (norm+relu) ----
    k_gemm<<<ggrid, 256, 0, stream>>>(x, W1, Hb, N);
    k_gather<<<agrid, 256, 0, stream>>>(Hb, rowptr, colA, valA, degw, b1, P, N);
    k_zero<<<1, 256, 0, stream>>>((int*)stats, 256);
    k_bnstats<<<512, 256, 0, stream>>>(P, sums, sumsq, N);
    k_bnapply<<<pgrid, 256, 0, stream>>>(P, sums, sumsq, g1, be1, P, N, invN, 1);

    // ---- layer 2 ----
    k_gemm<<<ggrid, 256, 0, stream>>>(P, W2, Hb, N);
    k_gather<<<agrid, 256, 0, stream>>>(Hb, rowptr, colA, valA, degw, b2, P, N);
    k_zero<<<1, 256, 0, stream>>>((int*)stats, 256);
    k_bnstats<<<512, 256, 0, stream>>>(P, sums, sumsq, N);
    k_bnapply<<<pgrid, 256, 0, stream>>>(P, sums, sumsq, g2, be2, P, N, invN, 1);

    // ---- layer 3 (no relu) ----
    k_gemm<<<ggrid, 256, 0, stream>>>(P, W3, Hb, N);
    k_gather<<<agrid, 256, 0, stream>>>(Hb, rowptr, colA, valA, degw, b3, P, N);
    k_zero<<<1, 256, 0, stream>>>((int*)stats, 256);
    k_bnstats<<<512, 256, 0, stream>>>(P, sums, sumsq, N);
    k_bnapply<<<pgrid, 256, 0, stream>>>(P, sums, sumsq, g3, be3, P, N, invN, 0);
}

// Round 4
// 810.664 us; speedup vs baseline: 1.2433x; 1.2433x over previous
//
#include <hip/hip_runtime.h>

#define D 128
#define BN_EPS 1e-5f

typedef unsigned short u16;
typedef __attribute__((ext_vector_type(8))) short bf16x8;
typedef __attribute__((ext_vector_type(4))) float f32x4;

__device__ __forceinline__ float bf2f(u16 u) {
    unsigned v = (unsigned)u << 16; float f; __builtin_memcpy(&f, &v, 4); return f;
}
__device__ __forceinline__ u16 f2bf(float f) {
    unsigned v; __builtin_memcpy(&v, &f, 4);
    v += 0x7FFFu + ((v >> 16) & 1u);          // round-to-nearest-even
    return (u16)(v >> 16);
}

// ---------------- utility: zero an int/float buffer ----------------
__global__ __launch_bounds__(256) void k_zero(int* __restrict__ p, int n)
{
    int i = blockIdx.x * 256 + threadIdx.x;
    if (i < n) p[i] = 0;
}

// ---------------- preprocessing: degrees + CSR by dst ----------------
// NOTE: harness materializes integer inputs as int32 on device.
__global__ __launch_bounds__(256) void k_deg(const int* __restrict__ ei, const float* __restrict__ ew,
                                             float* __restrict__ degw, int* __restrict__ cnt, int E)
{
    int e = blockIdx.x * 256 + threadIdx.x;
    if (e >= E) return;
    int d = ei[(size_t)E + e];
    atomicAdd(&degw[d], ew[e]);
    atomicAdd(&cnt[d], 1);
}

__global__ __launch_bounds__(256) void k_dinv(float* __restrict__ degw, int N)
{
    int i = blockIdx.x * 256 + threadIdx.x;
    if (i < N) degw[i] = rsqrtf(degw[i] + 1.0f);   // +1 = self-loop weight
}

// single-block scan: exclusive prefix over cnt[0..N-1] -> rowptr[0..N]
__global__ __launch_bounds__(1024) void k_scan(const int* __restrict__ cnt, int* __restrict__ rowptr, int N)
{
    __shared__ int wsum[17];
    __shared__ int carry_s;
    int tid = threadIdx.x, lane = tid & 63, wid = tid >> 6;
    if (tid == 0) carry_s = 0;
    __syncthreads();
    for (int base = 0; base < N; base += 8192) {
        int i0 = base + tid * 8;
        int v[8], s[8];
        int run = 0;
#pragma unroll
        for (int j = 0; j < 8; ++j) {
            int i = i0 + j;
            v[j] = (i < N) ? cnt[i] : 0;
            run += v[j];
            s[j] = run;
        }
        int inc = run;
#pragma unroll
        for (int off = 1; off < 64; off <<= 1) {
            int t = __shfl_up(inc, (unsigned)off, 64);
            if (lane >= off) inc += t;
        }
        if (lane == 63) wsum[wid] = inc;
        __syncthreads();
        if (wid == 0) {
            int w = (lane < 16) ? wsum[lane] : 0;
            int winc = w;
#pragma unroll
            for (int off = 1; off < 16; off <<= 1) {
                int t = __shfl_up(winc, (unsigned)off, 64);
                if (lane >= off) winc += t;
            }
            if (lane < 16) wsum[lane] = winc - w;
            if (lane == 15) wsum[16] = winc;
        }
        __syncthreads();
        int toff = carry_s + wsum[wid] + (inc - run);
#pragma unroll
        for (int j = 0; j < 8; ++j) {
            int i = i0 + j;
            if (i < N) rowptr[i] = toff + s[j] - v[j];
        }
        __syncthreads();
        if (tid == 0) carry_s += wsum[16];
        __syncthreads();
    }
    if (threadIdx.x == 0) rowptr[N] = carry_s;
}

__global__ __launch_bounds__(256) void k_fill(const int* __restrict__ ei, const float* __restrict__ ew,
                                              const float* __restrict__ dinv, const int* __restrict__ rowptr,
                                              int* __restrict__ fillc, int* __restrict__ col,
                                              float* __restrict__ val, int E)
{
    int e = blockIdx.x * 256 + threadIdx.x;
    if (e >= E) return;
    int s = ei[e];
    int d = ei[(size_t)E + e];
    float nrm = dinv[s] * ew[e] * dinv[d];
    int p = rowptr[d] + atomicAdd(&fillc[d], 1);
    col[p] = s;
    val[p] = nrm;
}

// ---------------- W^T -> bf16 (per layer, 128x128) ----------------
__global__ __launch_bounds__(256) void k_wt(const float* __restrict__ W, u16* __restrict__ Wt)
{
    int i = blockIdx.x * 256 + threadIdx.x;   // i = k*128 + c
    if (i >= D * D) return;
    int k = i >> 7, c = i & 127;
    Wt[c * D + k] = f2bf(W[i]);
}

// ---------------- MFMA GEMM: H[N,128](bf16) = X[N,128](f32) @ W ----------------
// block = 4 waves, 64 rows; wave owns 32 cols (2 16-col tiles), B frags in regs.
__global__ __launch_bounds__(256) void k_gemm(const float* __restrict__ X, const u16* __restrict__ Wt,
                                              u16* __restrict__ H, int N)
{
    int tid = threadIdx.x;
    int wv = tid >> 6, lane = tid & 63;
    int colA = lane & 15, oct = lane >> 4;
    int r0 = blockIdx.x * 64;
    int c0 = wv * 32;

    bf16x8 bfr[2][4];
#pragma unroll
    for (int t = 0; t < 2; ++t)
#pragma unroll
        for (int kk = 0; kk < 4; ++kk)
            bfr[t][kk] = *(const bf16x8*)(Wt + (size_t)(c0 + t * 16 + colA) * D + kk * 32 + oct * 8);

    for (int rs = 0; rs < 4; ++rs) {
        int r = r0 + rs * 16;
        int rr = r + colA; rr = rr < N ? rr : N - 1;          // clamp loads; stores guarded
        const float* xrow = X + (size_t)rr * D + oct * 8;
        f32x4 acc0 = {0.f, 0.f, 0.f, 0.f}, acc1 = {0.f, 0.f, 0.f, 0.f};
#pragma unroll
        for (int kk = 0; kk < 4; ++kk) {
            float4 xa = *(const float4*)(xrow + kk * 32);
            float4 xb = *(const float4*)(xrow + kk * 32 + 4);
            bf16x8 a;
            a[0] = (short)f2bf(xa.x); a[1] = (short)f2bf(xa.y);
            a[2] = (short)f2bf(xa.z); a[3] = (short)f2bf(xa.w);
            a[4] = (short)f2bf(xb.x); a[5] = (short)f2bf(xb.y);
            a[6] = (short)f2bf(xb.z); a[7] = (short)f2bf(xb.w);
            acc0 = __builtin_amdgcn_mfma_f32_16x16x32_bf16(a, bfr[0][kk], acc0, 0, 0, 0);
            acc1 = __builtin_amdgcn_mfma_f32_16x16x32_bf16(a, bfr[1][kk], acc1, 0, 0, 0);
        }
        int orow = r + oct * 4;                                // + j (reg idx)
        size_t obase = (size_t)orow * D + c0 + colA;
#pragma unroll
        for (int j = 0; j < 4; ++j) {
            if (orow + j < N) {
                H[obase + (size_t)j * D]      = f2bf(acc0[j]);
                H[obase + (size_t)j * D + 16] = f2bf(acc1[j]);
            }
        }
    }
}

// ---------------- aggregation: out[n] = sum norm_e * h[src_e] + dinv^2*h[n] + b ----
__global__ __launch_bounds__(256) void k_gather(const u16* __restrict__ h, const int* __restrict__ rowptr,
                                                const int* __restrict__ col, const float* __restrict__ val,
                                                const float* __restrict__ dinv, const float* __restrict__ bias,
                                                float* __restrict__ out, int N)
{
    int wid = blockIdx.x * 4 + (threadIdx.x >> 6);
    int lane = threadIdx.x & 63;
    if (wid >= N) return;
    float di = dinv[wid];
    float sw = di * di;
    ushort2 hv = ((const ushort2*)(h + (size_t)wid * D))[lane];
    float ax = bf2f(hv.x) * sw, ay = bf2f(hv.y) * sw;
    int j   = __builtin_amdgcn_readfirstlane(rowptr[wid]);
    int end = __builtin_amdgcn_readfirstlane(rowptr[wid + 1]);
    for (; j + 4 <= end; j += 4) {
        int s0 = col[j], s1 = col[j + 1], s2 = col[j + 2], s3 = col[j + 3];
        float w0 = val[j], w1 = val[j + 1], w2 = val[j + 2], w3 = val[j + 3];
        ushort2 v0 = ((const ushort2*)(h + (size_t)s0 * D))[lane];
        ushort2 v1 = ((const ushort2*)(h + (size_t)s1 * D))[lane];
        ushort2 v2 = ((const ushort2*)(h + (size_t)s2 * D))[lane];
        ushort2 v3 = ((const ushort2*)(h + (size_t)s3 * D))[lane];
        ax = fmaf(w0, bf2f(v0.x), ax); ay = fmaf(w0, bf2f(v0.y), ay);
        ax = fmaf(w1, bf2f(v1.x), ax); ay = fmaf(w1, bf2f(v1.y), ay);
        ax = fmaf(w2, bf2f(v2.x), ax); ay = fmaf(w2, bf2f(v2.y), ay);
        ax = fmaf(w3, bf2f(v3.x), ax); ay = fmaf(w3, bf2f(v3.y), ay);
    }
    for (; j < end; ++j) {
        int s0 = col[j]; float w0 = val[j];
        ushort2 v0 = ((const ushort2*)(h + (size_t)s0 * D))[lane];
        ax = fmaf(w0, bf2f(v0.x), ax); ay = fmaf(w0, bf2f(v0.y), ay);
    }
    float2 b = ((const float2*)bias)[lane];
    float2 o; o.x = ax + b.x; o.y = ay + b.y;
    ((float2*)(out + (size_t)wid * D))[lane] = o;
}

// ---------------- BatchNorm ----------------
__global__ __launch_bounds__(256) void k_bnstats(const float* __restrict__ x, float* __restrict__ sums,
                                                 float* __restrict__ sumsq, int N)
{
    int c = threadIdx.x & 127;
    int half = threadIdx.x >> 7;
    int stride = gridDim.x * 2;
    float s = 0.f, s2 = 0.f;
    for (int r = blockIdx.x * 2 + half; r < N; r += stride) {
        float v = x[(size_t)r * D + c];
        s += v; s2 = fmaf(v, v, s2);
    }
    __shared__ float ls[256], ls2[256];
    ls[threadIdx.x] = s; ls2[threadIdx.x] = s2;
    __syncthreads();
    if (half == 0) {
        s += ls[c + 128]; s2 += ls2[c + 128];
        atomicAdd(&sums[c], s);
        atomicAdd(&sumsq[c], s2);
    }
}

__global__ __launch_bounds__(256) void k_bnapply(const float* __restrict__ in, const float* __restrict__ sums,
                                                 const float* __restrict__ sumsq, const float* __restrict__ g,
                                                 const float* __restrict__ be, float* __restrict__ out,
                                                 int N, float invN, int relu)
{
    int idx = blockIdx.x * 256 + threadIdx.x;
    if (idx >= N * 32) return;
    int cc = idx & 31;
    float4 xv = ((const float4*)in)[idx];
    float4 sv = ((const float4*)sums)[cc];
    float4 qv = ((const float4*)sumsq)[cc];
    float4 gv = ((const float4*)g)[cc];
    float4 bv = ((const float4*)be)[cc];
    float4 o;
#define BN1(X, SS, QQ, GG, BB, OO)                                     \
    {                                                                  \
        float mu = SS * invN;                                          \
        float var = fmaxf(QQ * invN - mu * mu, 0.f);                   \
        float rs = rsqrtf(var + BN_EPS);                               \
        float y = (X - mu) * rs * GG + BB;                             \
        OO = relu ? fmaxf(y, 0.f) : y;                                 \
    }
    BN1(xv.x, sv.x, qv.x, gv.x, bv.x, o.x)
    BN1(xv.y, sv.y, qv.y, gv.y, bv.y, o.y)
    BN1(xv.z, sv.z, qv.z, gv.z, bv.z, o.z)
    BN1(xv.w, sv.w, qv.w, gv.w, bv.w, o.w)
#undef BN1
    ((float4*)out)[idx] = o;
}

// ---------------- launch ----------------
extern "C" void kernel_launch(void* const* d_in, const int* in_sizes, int n_in,
                              void* d_out, int out_size, void* d_ws, size_t ws_size,
                              hipStream_t stream)
{
    const float* x  = (const float*)d_in[0];
    const int*   ei = (const int*)d_in[1];      // int32 on device
    const float* ew = (const float*)d_in[2];
    const float* W1 = (const float*)d_in[4];
    const float* b1 = (const float*)d_in[5];
    const float* W2 = (const float*)d_in[6];
    const float* b2 = (const float*)d_in[7];
    const float* W3 = (const float*)d_in[8];
    const float* b3 = (const float*)d_in[9];
    const float* g1 = (const float*)d_in[10];
    const float* be1 = (const float*)d_in[11];
    const float* g2 = (const float*)d_in[12];
    const float* be2 = (const float*)d_in[13];
    const float* g3 = (const float*)d_in[14];
    const float* be3 = (const float*)d_in[15];

    int N = in_sizes[0] / D;
    int E = in_sizes[1] / 2;
    float* P = (float*)d_out;      // the only big f32 buffer (activations, in-place BN)

    char* ws = (char*)d_ws;
    size_t off = 0;
    auto alloc = [&](size_t bytes) -> void* {
        void* p = ws + off;
        off = (off + bytes + 255) & ~(size_t)255;
        return p;
    };
    u16*   Hb    = (u16*)alloc((size_t)N * D * 2);      // bf16 GEMM output, 25.6 MB
    float* degw  = (float*)alloc((size_t)N * 4);        // becomes dinv
    int*   cnt   = (int*)alloc((size_t)N * 4);
    int*   rowptr= (int*)alloc((size_t)(N + 1) * 4);
    int*   colA  = (int*)alloc((size_t)E * 4);
    float* valA  = (float*)alloc((size_t)E * 4);
    float* stats = (float*)alloc(1024);
    float* sums  = stats;
    float* sumsq = stats + 128;
    u16*   Wt1   = (u16*)alloc((size_t)D * D * 2);
    u16*   Wt2   = (u16*)alloc((size_t)D * D * 2);
    u16*   Wt3   = (u16*)alloc((size_t)D * D * 2);

    float invN = 1.0f / (float)N;
    int egrid = (E + 255) / 256;
    int ngrid = (N + 255) / 256;
    int ggrid = (N + 63) / 64;
    int agrid = (N + 3) / 4;
    int pgrid = (N * 32 + 255) / 256;
    int wgrid = (D * D + 255) / 256;

    // ---- CSR build + weight transposes ----
    k_zero<<<ngrid, 256, 0, stream>>>((int*)degw, N);
    k_zero<<<ngrid, 256, 0, stream>>>(cnt, N);
    k_deg<<<egrid, 256, 0, stream>>>(ei, ew, degw, cnt, E);
    k_dinv<<<ngrid, 256, 0, stream>>>(degw, N);
    k_scan<<<1, 1024, 0, stream>>>(cnt, rowptr, N);
    k_zero<<<ngrid, 256, 0, stream>>>(cnt, N);
    k_fill<<<egrid, 256, 0, stream>>>(ei, ew, degw, rowptr, cnt, colA, valA, E);
    k_wt<<<wgrid, 256, 0, stream>>>(W1, Wt1);
    k_wt<<<wgrid, 256, 0, stream>>>(W2, Wt2);
    k_wt<<<wgrid, 256, 0, stream>>>(W3, Wt3);

    // ---- layer 1: x -> Hb (gemm) -> P (agg) -> stats -> P in-place (norm+relu) ----
    k_gemm<<<ggrid, 256, 0, stream>>>(x, Wt1, Hb, N);
    k_gather<<<agrid, 256, 0, stream>>>(Hb, rowptr, colA, valA, degw, b1, P, N);
    k_zero<<<1, 256, 0, stream>>>((int*)stats, 256);
    k_bnstats<<<512, 256, 0, stream>>>(P, sums, sumsq, N);
    k_bnapply<<<pgrid, 256, 0, stream>>>(P, sums, sumsq, g1, be1, P, N, invN, 1);

    // ---- layer 2 ----
    k_gemm<<<ggrid, 256, 0, stream>>>(P, Wt2, Hb, N);
    k_gather<<<agrid, 256, 0, stream>>>(Hb, rowptr, colA, valA, degw, b2, P, N);
    k_zero<<<1, 256, 0, stream>>>((int*)stats, 256);
    k_bnstats<<<512, 256, 0, stream>>>(P, sums, sumsq, N);
    k_bnapply<<<pgrid, 256, 0, stream>>>(P, sums, sumsq, g2, be2, P, N, invN, 1);

    // ---- layer 3 (no relu) ----
    k_gemm<<<ggrid, 256, 0, stream>>>(P, Wt3, Hb, N);
    k_gather<<<agrid, 256, 0, stream>>>(Hb, rowptr, colA, valA, degw, b3, P, N);
    k_zero<<<1, 256, 0, stream>>>((int*)stats, 256);
    k_bnstats<<<512, 256, 0, stream>>>(P, sums, sumsq, N);
    k_bnapply<<<pgrid, 256, 0, stream>>>(P, sums, sumsq, g3, be3, P, N, invN, 0);
}

// Round 5
// 696.638 us; speedup vs baseline: 1.4468x; 1.1637x over previous
//
#include <hip/hip_runtime.h>

#define D 128
#define BN_EPS 1e-5f

typedef unsigned short u16;
typedef unsigned long long u64;
typedef __attribute__((ext_vector_type(8))) short bf16x8;
typedef __attribute__((ext_vector_type(4))) float f32x4;

#define FIX_SCALE 1073741824.0f          // 2^30
#define FIX_INV   (1.0f / 1073741824.0f)
#define CNT_SHIFT 42
#define W_MASK    ((1ULL << CNT_SHIFT) - 1)

__device__ __forceinline__ float bf2f(u16 u) {
    unsigned v = (unsigned)u << 16; float f; __builtin_memcpy(&f, &v, 4); return f;
}
__device__ __forceinline__ u16 f2bf(float f) {
    unsigned v; __builtin_memcpy(&v, &f, 4);
    v += 0x7FFFu + ((v >> 16) & 1u);          // round-to-nearest-even
    return (u16)(v >> 16);
}

// ---------------- utility: zero a buffer ----------------
__global__ __launch_bounds__(256) void k_zero(int* __restrict__ p, int n)
{
    int i = blockIdx.x * 256 + threadIdx.x;
    if (i < n) p[i] = 0;
}

// ---------------- degrees: ONE packed 64-bit atomic per edge ----------------
__global__ __launch_bounds__(256) void k_deg(const int* __restrict__ ei, const float* __restrict__ ew,
                                             u64* __restrict__ deg2, int E)
{
    int e = blockIdx.x * 256 + threadIdx.x;
    if (e >= E) return;
    int d = ei[(size_t)E + e];
    u64 pk = (1ULL << CNT_SHIFT) | (u64)(ew[e] * FIX_SCALE + 0.5f);
    atomicAdd(&deg2[d], pk);
}

// unpack: dinv[i] = rsqrt(wdeg+1), cnt[i] = count
__global__ __launch_bounds__(256) void k_dinv(const u64* __restrict__ deg2, float* __restrict__ dinv,
                                              int* __restrict__ cnt, int N)
{
    int i = blockIdx.x * 256 + threadIdx.x;
    if (i >= N) return;
    u64 v = deg2[i];
    cnt[i] = (int)(v >> CNT_SHIFT);
    float wdeg = (float)(v & W_MASK) * FIX_INV;
    dinv[i] = rsqrtf(wdeg + 1.0f);            // +1 = self-loop weight
}

// single-block scan: exclusive prefix over cnt[0..N-1] -> rowptr[0..N]
__global__ __launch_bounds__(1024) void k_scan(const int* __restrict__ cnt, int* __restrict__ rowptr, int N)
{
    __shared__ int wsum[17];
    __shared__ int carry_s;
    int tid = threadIdx.x, lane = tid & 63, wid = tid >> 6;
    if (tid == 0) carry_s = 0;
    __syncthreads();
    for (int base = 0; base < N; base += 8192) {
        int i0 = base + tid * 8;
        int v[8], s[8];
        int run = 0;
#pragma unroll
        for (int j = 0; j < 8; ++j) {
            int i = i0 + j;
            v[j] = (i < N) ? cnt[i] : 0;
            run += v[j];
            s[j] = run;
        }
        int inc = run;
#pragma unroll
        for (int off = 1; off < 64; off <<= 1) {
            int t = __shfl_up(inc, (unsigned)off, 64);
            if (lane >= off) inc += t;
        }
        if (lane == 63) wsum[wid] = inc;
        __syncthreads();
        if (wid == 0) {
            int w = (lane < 16) ? wsum[lane] : 0;
            int winc = w;
#pragma unroll
            for (int off = 1; off < 16; off <<= 1) {
                int t = __shfl_up(winc, (unsigned)off, 64);
                if (lane >= off) winc += t;
            }
            if (lane < 16) wsum[lane] = winc - w;
            if (lane == 15) wsum[16] = winc;
        }
        __syncthreads();
        int toff = carry_s + wsum[wid] + (inc - run);
#pragma unroll
        for (int j = 0; j < 8; ++j) {
            int i = i0 + j;
            if (i < N) rowptr[i] = toff + s[j] - v[j];
        }
        __syncthreads();
        if (tid == 0) carry_s += wsum[16];
        __syncthreads();
    }
    if (threadIdx.x == 0) rowptr[N] = carry_s;
}

// fill CSR: one int2 (col, val) store per edge
__global__ __launch_bounds__(256) void k_fill(const int* __restrict__ ei, const float* __restrict__ ew,
                                              const float* __restrict__ dinv, const int* __restrict__ rowptr,
                                              int* __restrict__ fillc, int2* __restrict__ cv, int E)
{
    int e = blockIdx.x * 256 + threadIdx.x;
    if (e >= E) return;
    int s = ei[e];
    int d = ei[(size_t)E + e];
    float nrm = dinv[s] * ew[e] * dinv[d];
    int p = rowptr[d] + atomicAdd(&fillc[d], 1);
    cv[p] = make_int2(s, __float_as_int(nrm));
}

// ---------------- W^T -> bf16 (per layer, 128x128) ----------------
__global__ __launch_bounds__(256) void k_wt(const float* __restrict__ W, u16* __restrict__ Wt)
{
    int i = blockIdx.x * 256 + threadIdx.x;   // i = k*128 + c
    if (i >= D * D) return;
    int k = i >> 7, c = i & 127;
    Wt[c * D + k] = f2bf(W[i]);
}

// ---------------- BN params: scale/shift from stats ----------------
__global__ __launch_bounds__(128) void k_bnparam(const float* __restrict__ sums, const float* __restrict__ sumsq,
                                                 const float* __restrict__ g, const float* __restrict__ be,
                                                 float* __restrict__ ss, float invN)
{
    int c = threadIdx.x;
    float mu = sums[c] * invN;
    float var = fmaxf(sumsq[c] * invN - mu * mu, 0.f);
    float rs = rsqrtf(var + BN_EPS);
    float sc = rs * g[c];
    ss[c] = sc;
    ss[D + c] = be[c] - mu * sc;
}

// ---------------- MFMA GEMM: H[N,128](bf16) = f(X[N,128](f32)) @ W ----------------
// FUSE_BN: f(x) = relu(x*scale[k] + shift[k]) (previous layer's BN+ReLU)
template <int FUSE_BN>
__global__ __launch_bounds__(256) void k_gemm(const float* __restrict__ X, const u16* __restrict__ Wt,
                                              u16* __restrict__ H, int N, const float* __restrict__ ss)
{
    int tid = threadIdx.x;
    int wv = tid >> 6, lane = tid & 63;
    int colA = lane & 15, oct = lane >> 4;
    int r0 = blockIdx.x * 64;
    int c0 = wv * 32;

    bf16x8 bfr[2][4];
#pragma unroll
    for (int t = 0; t < 2; ++t)
#pragma unroll
        for (int kk = 0; kk < 4; ++kk)
            bfr[t][kk] = *(const bf16x8*)(Wt + (size_t)(c0 + t * 16 + colA) * D + kk * 32 + oct * 8);

    float4 sc[8], sh[8];
    if (FUSE_BN) {
#pragma unroll
        for (int kk = 0; kk < 4; ++kk) {
            sc[kk * 2 + 0] = *(const float4*)(ss + kk * 32 + oct * 8);
            sc[kk * 2 + 1] = *(const float4*)(ss + kk * 32 + oct * 8 + 4);
            sh[kk * 2 + 0] = *(const float4*)(ss + D + kk * 32 + oct * 8);
            sh[kk * 2 + 1] = *(const float4*)(ss + D + kk * 32 + oct * 8 + 4);
        }
    }

    for (int rs = 0; rs < 4; ++rs) {
        int r = r0 + rs * 16;
        int rr = r + colA; rr = rr < N ? rr : N - 1;          // clamp loads; stores guarded
        const float* xrow = X + (size_t)rr * D + oct * 8;
        f32x4 acc0 = {0.f, 0.f, 0.f, 0.f}, acc1 = {0.f, 0.f, 0.f, 0.f};
#pragma unroll
        for (int kk = 0; kk < 4; ++kk) {
            float4 xa = *(const float4*)(xrow + kk * 32);
            float4 xb = *(const float4*)(xrow + kk * 32 + 4);
            if (FUSE_BN) {
                float4 s0 = sc[kk * 2], s1 = sc[kk * 2 + 1];
                float4 h0 = sh[kk * 2], h1 = sh[kk * 2 + 1];
                xa.x = fmaxf(fmaf(xa.x, s0.x, h0.x), 0.f);
                xa.y = fmaxf(fmaf(xa.y, s0.y, h0.y), 0.f);
                xa.z = fmaxf(fmaf(xa.z, s0.z, h0.z), 0.f);
                xa.w = fmaxf(fmaf(xa.w, s0.w, h0.w), 0.f);
                xb.x = fmaxf(fmaf(xb.x, s1.x, h1.x), 0.f);
                xb.y = fmaxf(fmaf(xb.y, s1.y, h1.y), 0.f);
                xb.z = fmaxf(fmaf(xb.z, s1.z, h1.z), 0.f);
                xb.w = fmaxf(fmaf(xb.w, s1.w, h1.w), 0.f);
            }
            bf16x8 a;
            a[0] = (short)f2bf(xa.x); a[1] = (short)f2bf(xa.y);
            a[2] = (short)f2bf(xa.z); a[3] = (short)f2bf(xa.w);
            a[4] = (short)f2bf(xb.x); a[5] = (short)f2bf(xb.y);
            a[6] = (short)f2bf(xb.z); a[7] = (short)f2bf(xb.w);
            acc0 = __builtin_amdgcn_mfma_f32_16x16x32_bf16(a, bfr[0][kk], acc0, 0, 0, 0);
            acc1 = __builtin_amdgcn_mfma_f32_16x16x32_bf16(a, bfr[1][kk], acc1, 0, 0, 0);
        }
        int orow = r + oct * 4;
        size_t obase = (size_t)orow * D + c0 + colA;
#pragma unroll
        for (int j = 0; j < 4; ++j) {
            if (orow + j < N) {
                H[obase + (size_t)j * D]      = f2bf(acc0[j]);
                H[obase + (size_t)j * D + 16] = f2bf(acc1[j]);
            }
        }
    }
}

// ---------------- aggregation: out[n] = sum norm_e * h[src_e] + dinv^2*h[n] + b ----
__global__ __launch_bounds__(256) void k_gather(const u16* __restrict__ h, const int* __restrict__ rowptr,
                                                const int2* __restrict__ cv, const float* __restrict__ dinv,
                                                const float* __restrict__ bias, float* __restrict__ out, int N)
{
    int wid = blockIdx.x * 4 + (threadIdx.x >> 6);
    int lane = threadIdx.x & 63;
    if (wid >= N) return;
    float di = dinv[wid];
    float sw = di * di;
    ushort2 hv = ((const ushort2*)(h + (size_t)wid * D))[lane];
    float ax = bf2f(hv.x) * sw, ay = bf2f(hv.y) * sw;
    int j   = __builtin_amdgcn_readfirstlane(rowptr[wid]);
    int end = __builtin_amdgcn_readfirstlane(rowptr[wid + 1]);
    for (; j + 4 <= end; j += 4) {
        int2 e0 = cv[j], e1 = cv[j + 1], e2 = cv[j + 2], e3 = cv[j + 3];
        float w0 = __int_as_float(e0.y), w1 = __int_as_float(e1.y);
        float w2 = __int_as_float(e2.y), w3 = __int_as_float(e3.y);
        ushort2 v0 = ((const ushort2*)(h + (size_t)e0.x * D))[lane];
        ushort2 v1 = ((const ushort2*)(h + (size_t)e1.x * D))[lane];
        ushort2 v2 = ((const ushort2*)(h + (size_t)e2.x * D))[lane];
        ushort2 v3 = ((const ushort2*)(h + (size_t)e3.x * D))[lane];
        ax = fmaf(w0, bf2f(v0.x), ax); ay = fmaf(w0, bf2f(v0.y), ay);
        ax = fmaf(w1, bf2f(v1.x), ax); ay = fmaf(w1, bf2f(v1.y), ay);
        ax = fmaf(w2, bf2f(v2.x), ax); ay = fmaf(w2, bf2f(v2.y), ay);
        ax = fmaf(w3, bf2f(v3.x), ax); ay = fmaf(w3, bf2f(v3.y), ay);
    }
    for (; j < end; ++j) {
        int2 e0 = cv[j];
        float w0 = __int_as_float(e0.y);
        ushort2 v0 = ((const ushort2*)(h + (size_t)e0.x * D))[lane];
        ax = fmaf(w0, bf2f(v0.x), ax); ay = fmaf(w0, bf2f(v0.y), ay);
    }
    float2 b = ((const float2*)bias)[lane];
    float2 o; o.x = ax + b.x; o.y = ay + b.y;
    ((float2*)(out + (size_t)wid * D))[lane] = o;
}

// ---------------- BatchNorm stats ----------------
__global__ __launch_bounds__(256) void k_bnstats(const float* __restrict__ x, float* __restrict__ sums,
                                                 float* __restrict__ sumsq, int N)
{
    int c = threadIdx.x & 127;
    int half = threadIdx.x >> 7;
    int stride = gridDim.x * 2;
    float s = 0.f, s2 = 0.f;
    for (int r = blockIdx.x * 2 + half; r < N; r += stride) {
        float v = x[(size_t)r * D + c];
        s += v; s2 = fmaf(v, v, s2);
    }
    __shared__ float ls[256], ls2[256];
    ls[threadIdx.x] = s; ls2[threadIdx.x] = s2;
    __syncthreads();
    if (half == 0) {
        s += ls[c + 128]; s2 += ls2[c + 128];
        atomicAdd(&sums[c], s);
        atomicAdd(&sumsq[c], s2);
    }
}

// final BN apply (layer 3 only, no relu)
__global__ __launch_bounds__(256) void k_bnapply(const float* __restrict__ in, const float* __restrict__ sums,
                                                 const float* __restrict__ sumsq, const float* __restrict__ g,
                                                 const float* __restrict__ be, float* __restrict__ out,
                                                 int N, float invN)
{
    int idx = blockIdx.x * 256 + threadIdx.x;
    if (idx >= N * 32) return;
    int cc = idx & 31;
    float4 xv = ((const float4*)in)[idx];
    float4 sv = ((const float4*)sums)[cc];
    float4 qv = ((const float4*)sumsq)[cc];
    float4 gv = ((const float4*)g)[cc];
    float4 bv = ((const float4*)be)[cc];
    float4 o;
#define BN1(X, SS, QQ, GG, BB, OO)                                     \
    {                                                                  \
        float mu = SS * invN;                                          \
        float var = fmaxf(QQ * invN - mu * mu, 0.f);                   \
        float rs = rsqrtf(var + BN_EPS);                               \
        OO = (X - mu) * rs * GG + BB;                                  \
    }
    BN1(xv.x, sv.x, qv.x, gv.x, bv.x, o.x)
    BN1(xv.y, sv.y, qv.y, gv.y, bv.y, o.y)
    BN1(xv.z, sv.z, qv.z, gv.z, bv.z, o.z)
    BN1(xv.w, sv.w, qv.w, gv.w, bv.w, o.w)
#undef BN1
    ((float4*)out)[idx] = o;
}

// ---------------- launch ----------------
extern "C" void kernel_launch(void* const* d_in, const int* in_sizes, int n_in,
                              void* d_out, int out_size, void* d_ws, size_t ws_size,
                              hipStream_t stream)
{
    const float* x  = (const float*)d_in[0];
    const int*   ei = (const int*)d_in[1];      // int32 on device
    const float* ew = (const float*)d_in[2];
    const float* W1 = (const float*)d_in[4];
    const float* b1 = (const float*)d_in[5];
    const float* W2 = (const float*)d_in[6];
    const float* b2 = (const float*)d_in[7];
    const float* W3 = (const float*)d_in[8];
    const float* b3 = (const float*)d_in[9];
    const float* g1 = (const float*)d_in[10];
    const float* be1 = (const float*)d_in[11];
    const float* g2 = (const float*)d_in[12];
    const float* be2 = (const float*)d_in[13];
    const float* g3 = (const float*)d_in[14];
    const float* be3 = (const float*)d_in[15];

    int N = in_sizes[0] / D;
    int E = in_sizes[1] / 2;
    float* P = (float*)d_out;      // the only big f32 buffer (activations)

    char* ws = (char*)d_ws;
    size_t off = 0;
    auto alloc = [&](size_t bytes) -> void* {
        void* p = ws + off;
        off = (off + bytes + 255) & ~(size_t)255;
        return p;
    };
    u16*   Hb    = (u16*)alloc((size_t)N * D * 2);      // bf16 GEMM output
    u64*   deg2  = (u64*)alloc((size_t)N * 8);          // packed (count, wdeg)
    float* dinv  = (float*)alloc((size_t)N * 4);
    int*   cnt   = (int*)alloc((size_t)N * 4);
    int*   rowptr= (int*)alloc((size_t)(N + 1) * 4);
    int2*  cv    = (int2*)alloc((size_t)E * 8);         // (col, val) pairs
    float* stats = (float*)alloc(1024);
    float* sums  = stats;
    float* sumsq = stats + 128;
    float* ss1   = (float*)alloc(1024);                 // scale[128] ++ shift[128]
    float* ss2   = (float*)alloc(1024);
    u16*   Wt1   = (u16*)alloc((size_t)D * D * 2);
    u16*   Wt2   = (u16*)alloc((size_t)D * D * 2);
    u16*   Wt3   = (u16*)alloc((size_t)D * D * 2);

    float invN = 1.0f / (float)N;
    int egrid = (E + 255) / 256;
    int ngrid = (N + 255) / 256;
    int ggrid = (N + 63) / 64;
    int agrid = (N + 3) / 4;
    int pgrid = (N * 32 + 255) / 256;
    int wgrid = (D * D + 255) / 256;

    // ---- CSR build + weight transposes ----
    k_zero<<<(2 * N + 255) / 256, 256, 0, stream>>>((int*)deg2, 2 * N);
    k_deg<<<egrid, 256, 0, stream>>>(ei, ew, deg2, E);
    k_dinv<<<ngrid, 256, 0, stream>>>(deg2, dinv, cnt, N);
    k_scan<<<1, 1024, 0, stream>>>(cnt, rowptr, N);
    k_zero<<<ngrid, 256, 0, stream>>>(cnt, N);
    k_fill<<<egrid, 256, 0, stream>>>(ei, ew, dinv, rowptr, cnt, cv, E);
    k_wt<<<wgrid, 256, 0, stream>>>(W1, Wt1);
    k_wt<<<wgrid, 256, 0, stream>>>(W2, Wt2);
    k_wt<<<wgrid, 256, 0, stream>>>(W3, Wt3);

    // ---- layer 1: x -> Hb -> P(agg) -> stats -> ss1 ----
    k_gemm<0><<<ggrid, 256, 0, stream>>>(x, Wt1, Hb, N, nullptr);
    k_gather<<<agrid, 256, 0, stream>>>(Hb, rowptr, cv, dinv, b1, P, N);
    k_zero<<<1, 256, 0, stream>>>((int*)stats, 256);
    k_bnstats<<<512, 256, 0, stream>>>(P, sums, sumsq, N);
    k_bnparam<<<1, 128, 0, stream>>>(sums, sumsq, g1, be1, ss1, invN);

    // ---- layer 2: BN1+ReLU fused into gemm ----
    k_gemm<1><<<ggrid, 256, 0, stream>>>(P, Wt2, Hb, N, ss1);
    k_gather<<<agrid, 256, 0, stream>>>(Hb, rowptr, cv, dinv, b2, P, N);
    k_zero<<<1, 256, 0, stream>>>((int*)stats, 256);
    k_bnstats<<<512, 256, 0, stream>>>(P, sums, sumsq, N);
    k_bnparam<<<1, 128, 0, stream>>>(sums, sumsq, g2, be2, ss2, invN);

    // ---- layer 3: BN2+ReLU fused into gemm; final BN applied explicitly ----
    k_gemm<1><<<ggrid, 256, 0, stream>>>(P, Wt3, Hb, N, ss2);
    k_gather<<<agrid, 256, 0, stream>>>(Hb, rowptr, cv, dinv, b3, P, N);
    k_zero<<<1, 256, 0, stream>>>((int*)stats, 256);
    k_bnstats<<<512, 256, 0, stream>>>(P, sums, sumsq, N);
    k_bnapply<<<pgrid, 256, 0, stream>>>(P, sums, sumsq, g3, be3, P, N, invN);
}

// Round 6
// 565.708 us; speedup vs baseline: 1.7817x; 1.2314x over previous
//
#include <hip/hip_runtime.h>

#define D 128
#define BN_EPS 1e-5f
#define STILE 2048

typedef unsigned short u16;
typedef unsigned long long u64;
typedef __attribute__((ext_vector_type(8))) short bf16x8;
typedef __attribute__((ext_vector_type(4))) float f32x4;

#define FIX_SCALE 1073741824.0f          // 2^30
#define FIX_INV   (1.0f / 1073741824.0f)
#define CNT_SHIFT 42
#define W_MASK    ((1ULL << CNT_SHIFT) - 1)

__device__ __forceinline__ float bf2f(u16 u) {
    unsigned v = (unsigned)u << 16; float f; __builtin_memcpy(&f, &v, 4); return f;
}
__device__ __forceinline__ u16 f2bf(float f) {
    unsigned v; __builtin_memcpy(&v, &f, 4);
    v += 0x7FFFu + ((v >> 16) & 1u);          // round-to-nearest-even
    return (u16)(v >> 16);
}

// ---------------- utility: zero a buffer ----------------
__global__ __launch_bounds__(256) void k_zero(int* __restrict__ p, int n)
{
    int i = blockIdx.x * 256 + threadIdx.x;
    if (i < n) p[i] = 0;
}

// ---------------- degrees: ONE packed 64-bit atomic per edge; old value -> slot ----------------
__global__ __launch_bounds__(256) void k_deg(const int* __restrict__ ei, const float* __restrict__ ew,
                                             u64* __restrict__ deg2, int* __restrict__ slot, int E)
{
    int e = blockIdx.x * 256 + threadIdx.x;
    if (e >= E) return;
    int d = ei[(size_t)E + e];
    u64 pk = (1ULL << CNT_SHIFT) | (u64)(ew[e] * FIX_SCALE + 0.5f);
    u64 old = atomicAdd(&deg2[d], pk);
    slot[e] = (int)(old >> CNT_SHIFT);        // this edge's rank within its dst row
}

// unpack: dinv[i] = rsqrt(wdeg+1), cnt[i] = count
__global__ __launch_bounds__(256) void k_dinv(const u64* __restrict__ deg2, float* __restrict__ dinv,
                                              int* __restrict__ cnt, int N)
{
    int i = blockIdx.x * 256 + threadIdx.x;
    if (i >= N) return;
    u64 v = deg2[i];
    cnt[i] = (int)(v >> CNT_SHIFT);
    float wdeg = (float)(v & W_MASK) * FIX_INV;
    dinv[i] = rsqrtf(wdeg + 1.0f);            // +1 = self-loop weight
}

// ---------------- hierarchical scan: cnt -> exclusive rowptr ----------------
// scan1: per-block (2048 elems) local exclusive scan + block totals
__global__ __launch_bounds__(256) void k_scan1(const int* __restrict__ cnt, int* __restrict__ rowptr,
                                               int* __restrict__ bsum, int N)
{
    __shared__ int wsum[4];
    int tid = threadIdx.x, lane = tid & 63, wid = tid >> 6;
    int i0 = blockIdx.x * STILE + tid * 8;
    int v[8]; int run = 0;
#pragma unroll
    for (int j = 0; j < 8; ++j) { int i = i0 + j; v[j] = (i < N) ? cnt[i] : 0; run += v[j]; }
    int inc = run;
#pragma unroll
    for (int off = 1; off < 64; off <<= 1) {
        int t = __shfl_up(inc, (unsigned)off, 64);
        if (lane >= off) inc += t;
    }
    if (lane == 63) wsum[wid] = inc;
    __syncthreads();
    int woff = 0;
#pragma unroll
    for (int w = 0; w < 4; ++w) woff += (w < wid) ? wsum[w] : 0;
    int toff = woff + inc - run;              // exclusive offset of this thread within block
    int s = 0;
#pragma unroll
    for (int j = 0; j < 8; ++j) {
        int i = i0 + j;
        if (i < N) rowptr[i] = toff + s;
        s += v[j];
    }
    if (tid == 255) bsum[blockIdx.x] = woff + inc;   // block total
}

// scan2: single wave scans the block totals in-place (exclusive); writes rowptr[N]
__global__ __launch_bounds__(64) void k_scan2(int* __restrict__ bsum, int* __restrict__ rowptrN, int nb)
{
    int lane = threadIdx.x;
    int carry = 0;
    for (int base = 0; base < nb; base += 64) {
        int i = base + lane;
        int v = (i < nb) ? bsum[i] : 0;
        int inc = v;
#pragma unroll
        for (int off = 1; off < 64; off <<= 1) {
            int t = __shfl_up(inc, (unsigned)off, 64);
            if (lane >= off) inc += t;
        }
        if (i < nb) bsum[i] = carry + inc - v;
        carry += __shfl(inc, 63, 64);
    }
    if (lane == 0) *rowptrN = carry;
}

// scan3: add block offsets
__global__ __launch_bounds__(256) void k_scan3(int* __restrict__ rowptr, const int* __restrict__ bsum, int N)
{
    int i = blockIdx.x * 256 + threadIdx.x;
    if (i < N) rowptr[i] += bsum[i >> 11];
}

// fill CSR: NO atomics (slot precomputed by k_deg)
__global__ __launch_bounds__(256) void k_fill(const int* __restrict__ ei, const float* __restrict__ ew,
                                              const float* __restrict__ dinv, const int* __restrict__ rowptr,
                                              const int* __restrict__ slot, int2* __restrict__ cv, int E)
{
    int e = blockIdx.x * 256 + threadIdx.x;
    if (e >= E) return;
    int s = ei[e];
    int d = ei[(size_t)E + e];
    float nrm = dinv[s] * ew[e] * dinv[d];
    int p = rowptr[d] + slot[e];
    cv[p] = make_int2(s, __float_as_int(nrm));
}

// ---------------- W^T -> bf16 (per layer, 128x128) ----------------
__global__ __launch_bounds__(256) void k_wt(const float* __restrict__ W, u16* __restrict__ Wt)
{
    int i = blockIdx.x * 256 + threadIdx.x;   // i = k*128 + c
    if (i >= D * D) return;
    int k = i >> 7, c = i & 127;
    Wt[c * D + k] = f2bf(W[i]);
}

// ---------------- BN params: scale/shift from stats ----------------
__global__ __launch_bounds__(128) void k_bnparam(const float* __restrict__ sums, const float* __restrict__ sumsq,
                                                 const float* __restrict__ g, const float* __restrict__ be,
                                                 float* __restrict__ ss, float invN)
{
    int c = threadIdx.x;
    float mu = sums[c] * invN;
    float var = fmaxf(sumsq[c] * invN - mu * mu, 0.f);
    float rs = rsqrtf(var + BN_EPS);
    float sc = rs * g[c];
    ss[c] = sc;
    ss[D + c] = be[c] - mu * sc;
}

// ---------------- MFMA GEMM: H[N,128](bf16) = f(X[N,128](f32)) @ W ----------------
template <int FUSE_BN>
__global__ __launch_bounds__(256) void k_gemm(const float* __restrict__ X, const u16* __restrict__ Wt,
                                              u16* __restrict__ H, int N, const float* __restrict__ ss)
{
    int tid = threadIdx.x;
    int wv = tid >> 6, lane = tid & 63;
    int colA = lane & 15, oct = lane >> 4;
    int r0 = blockIdx.x * 64;
    int c0 = wv * 32;

    bf16x8 bfr[2][4];
#pragma unroll
    for (int t = 0; t < 2; ++t)
#pragma unroll
        for (int kk = 0; kk < 4; ++kk)
            bfr[t][kk] = *(const bf16x8*)(Wt + (size_t)(c0 + t * 16 + colA) * D + kk * 32 + oct * 8);

    float4 sc[8], sh[8];
    if (FUSE_BN) {
#pragma unroll
        for (int kk = 0; kk < 4; ++kk) {
            sc[kk * 2 + 0] = *(const float4*)(ss + kk * 32 + oct * 8);
            sc[kk * 2 + 1] = *(const float4*)(ss + kk * 32 + oct * 8 + 4);
            sh[kk * 2 + 0] = *(const float4*)(ss + D + kk * 32 + oct * 8);
            sh[kk * 2 + 1] = *(const float4*)(ss + D + kk * 32 + oct * 8 + 4);
        }
    }

    for (int rs = 0; rs < 4; ++rs) {
        int r = r0 + rs * 16;
        int rr = r + colA; rr = rr < N ? rr : N - 1;          // clamp loads; stores guarded
        const float* xrow = X + (size_t)rr * D + oct * 8;
        f32x4 acc0 = {0.f, 0.f, 0.f, 0.f}, acc1 = {0.f, 0.f, 0.f, 0.f};
#pragma unroll
        for (int kk = 0; kk < 4; ++kk) {
            float4 xa = *(const float4*)(xrow + kk * 32);
            float4 xb = *(const float4*)(xrow + kk * 32 + 4);
            if (FUSE_BN) {
                float4 s0 = sc[kk * 2], s1 = sc[kk * 2 + 1];
                float4 h0 = sh[kk * 2], h1 = sh[kk * 2 + 1];
                xa.x = fmaxf(fmaf(xa.x, s0.x, h0.x), 0.f);
                xa.y = fmaxf(fmaf(xa.y, s0.y, h0.y), 0.f);
                xa.z = fmaxf(fmaf(xa.z, s0.z, h0.z), 0.f);
                xa.w = fmaxf(fmaf(xa.w, s0.w, h0.w), 0.f);
                xb.x = fmaxf(fmaf(xb.x, s1.x, h1.x), 0.f);
                xb.y = fmaxf(fmaf(xb.y, s1.y, h1.y), 0.f);
                xb.z = fmaxf(fmaf(xb.z, s1.z, h1.z), 0.f);
                xb.w = fmaxf(fmaf(xb.w, s1.w, h1.w), 0.f);
            }
            bf16x8 a;
            a[0] = (short)f2bf(xa.x); a[1] = (short)f2bf(xa.y);
            a[2] = (short)f2bf(xa.z); a[3] = (short)f2bf(xa.w);
            a[4] = (short)f2bf(xb.x); a[5] = (short)f2bf(xb.y);
            a[6] = (short)f2bf(xb.z); a[7] = (short)f2bf(xb.w);
            acc0 = __builtin_amdgcn_mfma_f32_16x16x32_bf16(a, bfr[0][kk], acc0, 0, 0, 0);
            acc1 = __builtin_amdgcn_mfma_f32_16x16x32_bf16(a, bfr[1][kk], acc1, 0, 0, 0);
        }
        int orow = r + oct * 4;
        size_t obase = (size_t)orow * D + c0 + colA;
#pragma unroll
        for (int j = 0; j < 4; ++j) {
            if (orow + j < N) {
                H[obase + (size_t)j * D]      = f2bf(acc0[j]);
                H[obase + (size_t)j * D + 16] = f2bf(acc1[j]);
            }
        }
    }
}

// ---------------- aggregation: out[n] = sum norm_e * h[src_e] + dinv^2*h[n] + b ----
__global__ __launch_bounds__(256) void k_gather(const u16* __restrict__ h, const int* __restrict__ rowptr,
                                                const int2* __restrict__ cv, const float* __restrict__ dinv,
                                                const float* __restrict__ bias, float* __restrict__ out, int N)
{
    int wid = blockIdx.x * 4 + (threadIdx.x >> 6);
    int lane = threadIdx.x & 63;
    if (wid >= N) return;
    float di = dinv[wid];
    float sw = di * di;
    ushort2 hv = ((const ushort2*)(h + (size_t)wid * D))[lane];
    float ax = bf2f(hv.x) * sw, ay = bf2f(hv.y) * sw;
    int j   = __builtin_amdgcn_readfirstlane(rowptr[wid]);
    int end = __builtin_amdgcn_readfirstlane(rowptr[wid + 1]);
    for (; j + 4 <= end; j += 4) {
        int2 e0 = cv[j], e1 = cv[j + 1], e2 = cv[j + 2], e3 = cv[j + 3];
        float w0 = __int_as_float(e0.y), w1 = __int_as_float(e1.y);
        float w2 = __int_as_float(e2.y), w3 = __int_as_float(e3.y);
        ushort2 v0 = ((const ushort2*)(h + (size_t)e0.x * D))[lane];
        ushort2 v1 = ((const ushort2*)(h + (size_t)e1.x * D))[lane];
        ushort2 v2 = ((const ushort2*)(h + (size_t)e2.x * D))[lane];
        ushort2 v3 = ((const ushort2*)(h + (size_t)e3.x * D))[lane];
        ax = fmaf(w0, bf2f(v0.x), ax); ay = fmaf(w0, bf2f(v0.y), ay);
        ax = fmaf(w1, bf2f(v1.x), ax); ay = fmaf(w1, bf2f(v1.y), ay);
        ax = fmaf(w2, bf2f(v2.x), ax); ay = fmaf(w2, bf2f(v2.y), ay);
        ax = fmaf(w3, bf2f(v3.x), ax); ay = fmaf(w3, bf2f(v3.y), ay);
    }
    for (; j < end; ++j) {
        int2 e0 = cv[j];
        float w0 = __int_as_float(e0.y);
        ushort2 v0 = ((const ushort2*)(h + (size_t)e0.x * D))[lane];
        ax = fmaf(w0, bf2f(v0.x), ax); ay = fmaf(w0, bf2f(v0.y), ay);
    }
    float2 b = ((const float2*)bias)[lane];
    float2 o; o.x = ax + b.x; o.y = ay + b.y;
    ((float2*)(out + (size_t)wid * D))[lane] = o;
}

// ---------------- BatchNorm stats ----------------
__global__ __launch_bounds__(256) void k_bnstats(const float* __restrict__ x, float* __restrict__ sums,
                                                 float* __restrict__ sumsq, int N)
{
    int c = threadIdx.x & 127;
    int half = threadIdx.x >> 7;
    int stride = gridDim.x * 2;
    float s = 0.f, s2 = 0.f;
    for (int r = blockIdx.x * 2 + half; r < N; r += stride) {
        float v = x[(size_t)r * D + c];
        s += v; s2 = fmaf(v, v, s2);
    }
    __shared__ float ls[256], ls2[256];
    ls[threadIdx.x] = s; ls2[threadIdx.x] = s2;
    __syncthreads();
    if (half == 0) {
        s += ls[c + 128]; s2 += ls2[c + 128];
        atomicAdd(&sums[c], s);
        atomicAdd(&sumsq[c], s2);
    }
}

// final BN apply (layer 3 only, no relu)
__global__ __launch_bounds__(256) void k_bnapply(const float* __restrict__ in, const float* __restrict__ sums,
                                                 const float* __restrict__ sumsq, const float* __restrict__ g,
                                                 const float* __restrict__ be, float* __restrict__ out,
                                                 int N, float invN)
{
    int idx = blockIdx.x * 256 + threadIdx.x;
    if (idx >= N * 32) return;
    int cc = idx & 31;
    float4 xv = ((const float4*)in)[idx];
    float4 sv = ((const float4*)sums)[cc];
    float4 qv = ((const float4*)sumsq)[cc];
    float4 gv = ((const float4*)g)[cc];
    float4 bv = ((const float4*)be)[cc];
    float4 o;
#define BN1(X, SS, QQ, GG, BB, OO)                                     \
    {                                                                  \
        float mu = SS * invN;                                          \
        float var = fmaxf(QQ * invN - mu * mu, 0.f);                   \
        float rs = rsqrtf(var + BN_EPS);                               \
        OO = (X - mu) * rs * GG + BB;                                  \
    }
    BN1(xv.x, sv.x, qv.x, gv.x, bv.x, o.x)
    BN1(xv.y, sv.y, qv.y, gv.y, bv.y, o.y)
    BN1(xv.z, sv.z, qv.z, gv.z, bv.z, o.z)
    BN1(xv.w, sv.w, qv.w, gv.w, bv.w, o.w)
#undef BN1
    ((float4*)out)[idx] = o;
}

// ---------------- launch ----------------
extern "C" void kernel_launch(void* const* d_in, const int* in_sizes, int n_in,
                              void* d_out, int out_size, void* d_ws, size_t ws_size,
                              hipStream_t stream)
{
    const float* x  = (const float*)d_in[0];
    const int*   ei = (const int*)d_in[1];      // int32 on device
    const float* ew = (const float*)d_in[2];
    const float* W1 = (const float*)d_in[4];
    const float* b1 = (const float*)d_in[5];
    const float* W2 = (const float*)d_in[6];
    const float* b2 = (const float*)d_in[7];
    const float* W3 = (const float*)d_in[8];
    const float* b3 = (const float*)d_in[9];
    const float* g1 = (const float*)d_in[10];
    const float* be1 = (const float*)d_in[11];
    const float* g2 = (const float*)d_in[12];
    const float* be2 = (const float*)d_in[13];
    const float* g3 = (const float*)d_in[14];
    const float* be3 = (const float*)d_in[15];

    int N = in_sizes[0] / D;
    int E = in_sizes[1] / 2;
    float* P = (float*)d_out;      // the only big f32 buffer (activations)

    char* ws = (char*)d_ws;
    size_t off = 0;
    auto alloc = [&](size_t bytes) -> void* {
        void* p = ws + off;
        off = (off + bytes + 255) & ~(size_t)255;
        return p;
    };
    u16*   Hb    = (u16*)alloc((size_t)N * D * 2);      // bf16 GEMM output
    u64*   deg2  = (u64*)alloc((size_t)N * 8);          // packed (count, wdeg)
    float* dinv  = (float*)alloc((size_t)N * 4);
    int*   cnt   = (int*)alloc((size_t)N * 4);
    int*   rowptr= (int*)alloc((size_t)(N + 1) * 4);
    int2*  cv    = (int2*)alloc((size_t)E * 8);         // (col, val) pairs
    int*   bsum  = (int*)alloc(((size_t)(100000 / STILE) + 2) * 4);
    float* stats = (float*)alloc(1024);
    float* sums  = stats;
    float* sumsq = stats + 128;
    float* ss1   = (float*)alloc(1024);                 // scale[128] ++ shift[128]
    float* ss2   = (float*)alloc(1024);
    u16*   Wt1   = (u16*)alloc((size_t)D * D * 2);
    u16*   Wt2   = (u16*)alloc((size_t)D * D * 2);
    u16*   Wt3   = (u16*)alloc((size_t)D * D * 2);
    int*   slot  = (int*)Hb;       // overlay: slot (E ints, 6.4MB) dies before first gemm uses Hb

    float invN = 1.0f / (float)N;
    int egrid = (E + 255) / 256;
    int ngrid = (N + 255) / 256;
    int ggrid = (N + 63) / 64;
    int agrid = (N + 3) / 4;
    int pgrid = (N * 32 + 255) / 256;
    int wgrid = (D * D + 255) / 256;
    int nb    = (N + STILE - 1) / STILE;

    // ---- CSR build + weight transposes ----
    k_zero<<<(2 * N + 255) / 256, 256, 0, stream>>>((int*)deg2, 2 * N);
    k_deg<<<egrid, 256, 0, stream>>>(ei, ew, deg2, slot, E);
    k_dinv<<<ngrid, 256, 0, stream>>>(deg2, dinv, cnt, N);
    k_scan1<<<nb, 256, 0, stream>>>(cnt, rowptr, bsum, N);
    k_scan2<<<1, 64, 0, stream>>>(bsum, rowptr + N, nb);
    k_scan3<<<(N + 255) / 256, 256, 0, stream>>>(rowptr, bsum, N);
    k_fill<<<egrid, 256, 0, stream>>>(ei, ew, dinv, rowptr, slot, cv, E);
    k_wt<<<wgrid, 256, 0, stream>>>(W1, Wt1);
    k_wt<<<wgrid, 256, 0, stream>>>(W2, Wt2);
    k_wt<<<wgrid, 256, 0, stream>>>(W3, Wt3);

    // ---- layer 1: x -> Hb -> P(agg) -> stats -> ss1 ----
    k_gemm<0><<<ggrid, 256, 0, stream>>>(x, Wt1, Hb, N, nullptr);
    k_gather<<<agrid, 256, 0, stream>>>(Hb, rowptr, cv, dinv, b1, P, N);
    k_zero<<<1, 256, 0, stream>>>((int*)stats, 256);
    k_bnstats<<<512, 256, 0, stream>>>(P, sums, sumsq, N);
    k_bnparam<<<1, 128, 0, stream>>>(sums, sumsq, g1, be1, ss1, invN);

    // ---- layer 2: BN1+ReLU fused into gemm ----
    k_gemm<1><<<ggrid, 256, 0, stream>>>(P, Wt2, Hb, N, ss1);
    k_gather<<<agrid, 256, 0, stream>>>(Hb, rowptr, cv, dinv, b2, P, N);
    k_zero<<<1, 256, 0, stream>>>((int*)stats, 256);
    k_bnstats<<<512, 256, 0, stream>>>(P, sums, sumsq, N);
    k_bnparam<<<1, 128, 0, stream>>>(sums, sumsq, g2, be2, ss2, invN);

    // ---- layer 3: BN2+ReLU fused into gemm; final BN applied explicitly ----
    k_gemm<1><<<ggrid, 256, 0, stream>>>(P, Wt3, Hb, N, ss2);
    k_gather<<<agrid, 256, 0, stream>>>(Hb, rowptr, cv, dinv, b3, P, N);
    k_zero<<<1, 256, 0, stream>>>((int*)stats, 256);
    k_bnstats<<<512, 256, 0, stream>>>(P, sums, sumsq, N);
    k_bnapply<<<pgrid, 256, 0, stream>>>(P, sums, sumsq, g3, be3, P, N, invN);
}

// Round 7
// 476.475 us; speedup vs baseline: 2.1154x; 1.1873x over previous
//
#include <hip/hip_runtime.h>

#define D 128
#define BN_EPS 1e-5f
#define STILE 2048
#define PAD 4                      // deg2 bin spacing: one u64 per 32B sector
#define NBG 2048                   // gather grid blocks

typedef unsigned short u16;
typedef unsigned long long u64;
typedef __attribute__((ext_vector_type(8))) short bf16x8;
typedef __attribute__((ext_vector_type(4))) float f32x4;

#define FIX_SCALE 1073741824.0f          // 2^30
#define FIX_INV   (1.0f / 1073741824.0f)
#define CNT_SHIFT 42
#define W_MASK    ((1ULL << CNT_SHIFT) - 1)

__device__ __forceinline__ float bf2f(u16 u) {
    unsigned v = (unsigned)u << 16; float f; __builtin_memcpy(&f, &v, 4); return f;
}
__device__ __forceinline__ u16 f2bf(float f) {
    unsigned v; __builtin_memcpy(&v, &f, 4);
    v += 0x7FFFu + ((v >> 16) & 1u);          // round-to-nearest-even
    return (u16)(v >> 16);
}

// ---------------- utility: zero a buffer ----------------
__global__ __launch_bounds__(256) void k_zero(int* __restrict__ p, int n)
{
    int i = blockIdx.x * 256 + threadIdx.x;
    if (i < n) p[i] = 0;
}

// ---------------- degrees: one padded u64 atomic per edge; old value -> slot ----------------
__global__ __launch_bounds__(256) void k_deg(const int* __restrict__ ei, const float* __restrict__ ew,
                                             u64* __restrict__ deg2, int* __restrict__ slot, int E)
{
    int e = blockIdx.x * 256 + threadIdx.x;
    if (e >= E) return;
    int d = ei[(size_t)E + e];
    u64 pk = (1ULL << CNT_SHIFT) | (u64)(ew[e] * FIX_SCALE + 0.5f);
    u64 old = atomicAdd(&deg2[(size_t)d * PAD], pk);
    slot[e] = (int)(old >> CNT_SHIFT);        // this edge's rank within its dst row
}

// ---------------- scan1 (fused dinv): per-block local scan of counts + dinv ----------------
__global__ __launch_bounds__(256) void k_scan1(const u64* __restrict__ deg2, float* __restrict__ dinv,
                                               int* __restrict__ rowptr, int* __restrict__ bsum, int N)
{
    __shared__ int wsum[4];
    int tid = threadIdx.x, lane = tid & 63, wid = tid >> 6;
    int i0 = blockIdx.x * STILE + tid * 8;
    int v[8]; int run = 0;
#pragma unroll
    for (int j = 0; j < 8; ++j) {
        int i = i0 + j;
        if (i < N) {
            u64 pv = deg2[(size_t)i * PAD];
            v[j] = (int)(pv >> CNT_SHIFT);
            float wdeg = (float)(pv & W_MASK) * FIX_INV;
            dinv[i] = rsqrtf(wdeg + 1.0f);    // +1 = self-loop weight
        } else v[j] = 0;
        run += v[j];
    }
    int inc = run;
#pragma unroll
    for (int off = 1; off < 64; off <<= 1) {
        int t = __shfl_up(inc, (unsigned)off, 64);
        if (lane >= off) inc += t;
    }
    if (lane == 63) wsum[wid] = inc;
    __syncthreads();
    int woff = 0;
#pragma unroll
    for (int w = 0; w < 4; ++w) woff += (w < wid) ? wsum[w] : 0;
    int toff = woff + inc - run;
    int s = 0;
#pragma unroll
    for (int j = 0; j < 8; ++j) {
        int i = i0 + j;
        if (i < N) rowptr[i] = toff + s;
        s += v[j];
    }
    if (tid == 255) bsum[blockIdx.x] = woff + inc;
}

// scan2: single wave scans the block totals in-place (exclusive); writes rowptr[N]
__global__ __launch_bounds__(64) void k_scan2(int* __restrict__ bsum, int* __restrict__ rowptrN, int nb)
{
    int lane = threadIdx.x;
    int carry = 0;
    for (int base = 0; base < nb; base += 64) {
        int i = base + lane;
        int v = (i < nb) ? bsum[i] : 0;
        int inc = v;
#pragma unroll
        for (int off = 1; off < 64; off <<= 1) {
            int t = __shfl_up(inc, (unsigned)off, 64);
            if (lane >= off) inc += t;
        }
        if (i < nb) bsum[i] = carry + inc - v;
        carry += __shfl(inc, 63, 64);
    }
    if (lane == 0) *rowptrN = carry;
}

// scan3: add block offsets
__global__ __launch_bounds__(256) void k_scan3(int* __restrict__ rowptr, const int* __restrict__ bsum, int N)
{
    int i = blockIdx.x * 256 + threadIdx.x;
    if (i < N) rowptr[i] += bsum[i >> 11];
}

// fill CSR: no atomics (slot precomputed by k_deg)
__global__ __launch_bounds__(256) void k_fill(const int* __restrict__ ei, const float* __restrict__ ew,
                                              const float* __restrict__ dinv, const int* __restrict__ rowptr,
                                              const int* __restrict__ slot, int2* __restrict__ cv, int E)
{
    int e = blockIdx.x * 256 + threadIdx.x;
    if (e >= E) return;
    int s = ei[e];
    int d = ei[(size_t)E + e];
    float nrm = dinv[s] * ew[e] * dinv[d];
    int p = rowptr[d] + slot[e];
    cv[p] = make_int2(s, __float_as_int(nrm));
}

// ---------------- W^T -> bf16 (per layer, 128x128) ----------------
__global__ __launch_bounds__(256) void k_wt(const float* __restrict__ W, u16* __restrict__ Wt)
{
    int i = blockIdx.x * 256 + threadIdx.x;   // i = k*128 + c
    if (i >= D * D) return;
    int k = i >> 7, c = i & 127;
    Wt[c * D + k] = f2bf(W[i]);
}

// ---------------- MFMA GEMM: H[N,128](bf16) = f(X[N,128](f32)) @ W ----------------
template <int FUSE_BN>
__global__ __launch_bounds__(256) void k_gemm(const float* __restrict__ X, const u16* __restrict__ Wt,
                                              u16* __restrict__ H, int N, const float* __restrict__ ss)
{
    int tid = threadIdx.x;
    int wv = tid >> 6, lane = tid & 63;
    int colA = lane & 15, oct = lane >> 4;
    int r0 = blockIdx.x * 64;
    int c0 = wv * 32;

    bf16x8 bfr[2][4];
#pragma unroll
    for (int t = 0; t < 2; ++t)
#pragma unroll
        for (int kk = 0; kk < 4; ++kk)
            bfr[t][kk] = *(const bf16x8*)(Wt + (size_t)(c0 + t * 16 + colA) * D + kk * 32 + oct * 8);

    float4 sc[8], sh[8];
    if (FUSE_BN) {
#pragma unroll
        for (int kk = 0; kk < 4; ++kk) {
            sc[kk * 2 + 0] = *(const float4*)(ss + kk * 32 + oct * 8);
            sc[kk * 2 + 1] = *(const float4*)(ss + kk * 32 + oct * 8 + 4);
            sh[kk * 2 + 0] = *(const float4*)(ss + D + kk * 32 + oct * 8);
            sh[kk * 2 + 1] = *(const float4*)(ss + D + kk * 32 + oct * 8 + 4);
        }
    }

    for (int rs = 0; rs < 4; ++rs) {
        int r = r0 + rs * 16;
        int rr = r + colA; rr = rr < N ? rr : N - 1;          // clamp loads; stores guarded
        const float* xrow = X + (size_t)rr * D + oct * 8;
        f32x4 acc0 = {0.f, 0.f, 0.f, 0.f}, acc1 = {0.f, 0.f, 0.f, 0.f};
#pragma unroll
        for (int kk = 0; kk < 4; ++kk) {
            float4 xa = *(const float4*)(xrow + kk * 32);
            float4 xb = *(const float4*)(xrow + kk * 32 + 4);
            if (FUSE_BN) {
                float4 s0 = sc[kk * 2], s1 = sc[kk * 2 + 1];
                float4 h0 = sh[kk * 2], h1 = sh[kk * 2 + 1];
                xa.x = fmaxf(fmaf(xa.x, s0.x, h0.x), 0.f);
                xa.y = fmaxf(fmaf(xa.y, s0.y, h0.y), 0.f);
                xa.z = fmaxf(fmaf(xa.z, s0.z, h0.z), 0.f);
                xa.w = fmaxf(fmaf(xa.w, s0.w, h0.w), 0.f);
                xb.x = fmaxf(fmaf(xb.x, s1.x, h1.x), 0.f);
                xb.y = fmaxf(fmaf(xb.y, s1.y, h1.y), 0.f);
                xb.z = fmaxf(fmaf(xb.z, s1.z, h1.z), 0.f);
                xb.w = fmaxf(fmaf(xb.w, s1.w, h1.w), 0.f);
            }
            bf16x8 a;
            a[0] = (short)f2bf(xa.x); a[1] = (short)f2bf(xa.y);
            a[2] = (short)f2bf(xa.z); a[3] = (short)f2bf(xa.w);
            a[4] = (short)f2bf(xb.x); a[5] = (short)f2bf(xb.y);
            a[6] = (short)f2bf(xb.z); a[7] = (short)f2bf(xb.w);
            acc0 = __builtin_amdgcn_mfma_f32_16x16x32_bf16(a, bfr[0][kk], acc0, 0, 0, 0);
            acc1 = __builtin_amdgcn_mfma_f32_16x16x32_bf16(a, bfr[1][kk], acc1, 0, 0, 0);
        }
        int orow = r + oct * 4;
        size_t obase = (size_t)orow * D + c0 + colA;
#pragma unroll
        for (int j = 0; j < 4; ++j) {
            if (orow + j < N) {
                H[obase + (size_t)j * D]      = f2bf(acc0[j]);
                H[obase + (size_t)j * D + 16] = f2bf(acc1[j]);
            }
        }
    }
}

// ---------------- aggregation + fused BN partial stats ----------------
// grid-stride over rows; per-lane col sums in regs; one 1KB partial row per block.
__global__ __launch_bounds__(256) void k_gather(const u16* __restrict__ h, const int* __restrict__ rowptr,
                                                const int2* __restrict__ cv, const float* __restrict__ dinv,
                                                const float* __restrict__ bias, float* __restrict__ out,
                                                float* __restrict__ partial, int N, int nbg)
{
    int lane = threadIdx.x & 63, wv = threadIdx.x >> 6;
    float2 b = ((const float2*)bias)[lane];
    float4 st = {0.f, 0.f, 0.f, 0.f};         // sum(c0), sumsq(c0), sum(c1), sumsq(c1)
    for (int wid = blockIdx.x * 4 + wv; wid < N; wid += nbg * 4) {
        float di = dinv[wid];
        float sw = di * di;
        ushort2 hv = ((const ushort2*)(h + (size_t)wid * D))[lane];
        float ax = bf2f(hv.x) * sw, ay = bf2f(hv.y) * sw;
        int j   = __builtin_amdgcn_readfirstlane(rowptr[wid]);
        int end = __builtin_amdgcn_readfirstlane(rowptr[wid + 1]);
        for (; j + 4 <= end; j += 4) {
            int2 e0 = cv[j], e1 = cv[j + 1], e2 = cv[j + 2], e3 = cv[j + 3];
            float w0 = __int_as_float(e0.y), w1 = __int_as_float(e1.y);
            float w2 = __int_as_float(e2.y), w3 = __int_as_float(e3.y);
            ushort2 v0 = ((const ushort2*)(h + (size_t)e0.x * D))[lane];
            ushort2 v1 = ((const ushort2*)(h + (size_t)e1.x * D))[lane];
            ushort2 v2 = ((const ushort2*)(h + (size_t)e2.x * D))[lane];
            ushort2 v3 = ((const ushort2*)(h + (size_t)e3.x * D))[lane];
            ax = fmaf(w0, bf2f(v0.x), ax); ay = fmaf(w0, bf2f(v0.y), ay);
            ax = fmaf(w1, bf2f(v1.x), ax); ay = fmaf(w1, bf2f(v1.y), ay);
            ax = fmaf(w2, bf2f(v2.x), ax); ay = fmaf(w2, bf2f(v2.y), ay);
            ax = fmaf(w3, bf2f(v3.x), ax); ay = fmaf(w3, bf2f(v3.y), ay);
        }
        for (; j < end; ++j) {
            int2 e0 = cv[j];
            float w0 = __int_as_float(e0.y);
            ushort2 v0 = ((const ushort2*)(h + (size_t)e0.x * D))[lane];
            ax = fmaf(w0, bf2f(v0.x), ax); ay = fmaf(w0, bf2f(v0.y), ay);
        }
        float ox = ax + b.x, oy = ay + b.y;
        float2 o; o.x = ox; o.y = oy;
        ((float2*)(out + (size_t)wid * D))[lane] = o;
        st.x += ox; st.y = fmaf(ox, ox, st.y);
        st.z += oy; st.w = fmaf(oy, oy, st.w);
    }
    __shared__ float4 red[4][64];
    red[wv][lane] = st;
    __syncthreads();
    if (wv == 0) {
        float4 a0 = red[0][lane], a1 = red[1][lane], a2 = red[2][lane], a3 = red[3][lane];
        float4 t;
        t.x = a0.x + a1.x + a2.x + a3.x;
        t.y = a0.y + a1.y + a2.y + a3.y;
        t.z = a0.z + a1.z + a2.z + a3.z;
        t.w = a0.w + a1.w + a2.w + a3.w;
        ((float4*)partial)[(size_t)blockIdx.x * 64 + lane] = t;
    }
}

// ---------------- reduce partials -> BN scale/shift ----------------
// partial[b][l*4+{0,1,2,3}] = sum(2l), sumsq(2l), sum(2l+1), sumsq(2l+1); block c handles col c.
__global__ __launch_bounds__(256) void k_bnred(const float* __restrict__ partial, int nbg,
                                               const float* __restrict__ g, const float* __restrict__ be,
                                               float* __restrict__ ss, float invN)
{
    int c = blockIdx.x;                        // 0..127
    int q = (c >> 1) * 4 + ((c & 1) << 1);     // offset of (sum, sumsq) pair in a partial row
    int t = threadIdx.x;
    float s = 0.f, s2 = 0.f;
    for (int bb = t; bb < nbg; bb += 256) {
        const float* row = partial + (size_t)bb * 256 + q;
        s += row[0]; s2 += row[1];
    }
#pragma unroll
    for (int off = 32; off; off >>= 1) {
        s  += __shfl_down(s,  (unsigned)off, 64);
        s2 += __shfl_down(s2, (unsigned)off, 64);
    }
    __shared__ float rs_[4], rq_[4];
    int wv = t >> 6, lane = t & 63;
    if (lane == 0) { rs_[wv] = s; rq_[wv] = s2; }
    __syncthreads();
    if (t == 0) {
        float S = rs_[0] + rs_[1] + rs_[2] + rs_[3];
        float Q = rq_[0] + rq_[1] + rq_[2] + rq_[3];
        float mu = S * invN;
        float var = fmaxf(Q * invN - mu * mu, 0.f);
        float r = rsqrtf(var + BN_EPS);
        float sc = r * g[c];
        ss[c] = sc;
        ss[D + c] = be[c] - mu * sc;
    }
}

// final BN apply (layer 3, no relu): y = x*sc + sh
__global__ __launch_bounds__(256) void k_bnapply(const float* __restrict__ in, const float* __restrict__ ss,
                                                 float* __restrict__ out, int N)
{
    int idx = blockIdx.x * 256 + threadIdx.x;
    if (idx >= N * 32) return;
    int cc = idx & 31;
    float4 xv = ((const float4*)in)[idx];
    float4 sc = ((const float4*)ss)[cc];
    float4 sh = ((const float4*)(ss + D))[cc];
    float4 o;
    o.x = fmaf(xv.x, sc.x, sh.x);
    o.y = fmaf(xv.y, sc.y, sh.y);
    o.z = fmaf(xv.z, sc.z, sh.z);
    o.w = fmaf(xv.w, sc.w, sh.w);
    ((float4*)out)[idx] = o;
}

// ---------------- launch ----------------
extern "C" void kernel_launch(void* const* d_in, const int* in_sizes, int n_in,
                              void* d_out, int out_size, void* d_ws, size_t ws_size,
                              hipStream_t stream)
{
    const float* x  = (const float*)d_in[0];
    const int*   ei = (const int*)d_in[1];      // int32 on device
    const float* ew = (const float*)d_in[2];
    const float* W1 = (const float*)d_in[4];
    const float* b1 = (const float*)d_in[5];
    const float* W2 = (const float*)d_in[6];
    const float* b2 = (const float*)d_in[7];
    const float* W3 = (const float*)d_in[8];
    const float* b3 = (const float*)d_in[9];
    const float* g1 = (const float*)d_in[10];
    const float* be1 = (const float*)d_in[11];
    const float* g2 = (const float*)d_in[12];
    const float* be2 = (const float*)d_in[13];
    const float* g3 = (const float*)d_in[14];
    const float* be3 = (const float*)d_in[15];

    int N = in_sizes[0] / D;
    int E = in_sizes[1] / 2;
    float* P = (float*)d_out;      // the only big f32 buffer (activations)

    char* ws = (char*)d_ws;
    size_t off = 0;
    auto alloc = [&](size_t bytes) -> void* {
        void* p = ws + off;
        off = (off + bytes + 255) & ~(size_t)255;
        return p;
    };
    u16*   Hb    = (u16*)alloc((size_t)N * D * 2);      // bf16 GEMM output
    float* dinv  = (float*)alloc((size_t)N * 4);
    int*   rowptr= (int*)alloc((size_t)(N + 1) * 4);
    int2*  cv    = (int2*)alloc((size_t)E * 8);         // (col, nrm) pairs; deg2 overlays
    float* partial = (float*)alloc((size_t)NBG * 256 * 4);
    int*   bsum  = (int*)alloc(((size_t)(N / STILE) + 2) * 4);
    float* ss1   = (float*)alloc(1024);                 // scale[128] ++ shift[128]
    float* ss2   = (float*)alloc(1024);
    float* ss3   = (float*)alloc(1024);
    u16*   Wt1   = (u16*)alloc((size_t)D * D * 2);
    u16*   Wt2   = (u16*)alloc((size_t)D * D * 2);
    u16*   Wt3   = (u16*)alloc((size_t)D * D * 2);
    u64*   deg2  = (u64*)cv;       // overlay: padded bins (N*32B <= E*8B); dies before k_fill writes cv
    int*   slot  = (int*)Hb;       // overlay: slot (E ints) dies before first gemm writes Hb

    float invN = 1.0f / (float)N;
    int egrid = (E + 255) / 256;
    int ggrid = (N + 63) / 64;
    int pgrid = (N * 32 + 255) / 256;
    int wgrid = (D * D + 255) / 256;
    int nb    = (N + STILE - 1) / STILE;
    int nbg   = NBG < (N + 3) / 4 ? NBG : (N + 3) / 4;

    // ---- CSR build + weight transposes ----
    k_zero<<<((N * PAD * 2) + 255) / 256, 256, 0, stream>>>((int*)deg2, N * PAD * 2);
    k_deg<<<egrid, 256, 0, stream>>>(ei, ew, deg2, slot, E);
    k_scan1<<<nb, 256, 0, stream>>>(deg2, dinv, rowptr, bsum, N);
    k_scan2<<<1, 64, 0, stream>>>(bsum, rowptr + N, nb);
    k_scan3<<<(N + 255) / 256, 256, 0, stream>>>(rowptr, bsum, N);
    k_fill<<<egrid, 256, 0, stream>>>(ei, ew, dinv, rowptr, slot, cv, E);
    k_wt<<<wgrid, 256, 0, stream>>>(W1, Wt1);
    k_wt<<<wgrid, 256, 0, stream>>>(W2, Wt2);
    k_wt<<<wgrid, 256, 0, stream>>>(W3, Wt3);

    // ---- layer 1 ----
    k_gemm<0><<<ggrid, 256, 0, stream>>>(x, Wt1, Hb, N, nullptr);
    k_gather<<<nbg, 256, 0, stream>>>(Hb, rowptr, cv, dinv, b1, P, partial, N, nbg);
    k_bnred<<<D, 256, 0, stream>>>(partial, nbg, g1, be1, ss1, invN);

    // ---- layer 2 (BN1+ReLU fused into gemm) ----
    k_gemm<1><<<ggrid, 256, 0, stream>>>(P, Wt2, Hb, N, ss1);
    k_gather<<<nbg, 256, 0, stream>>>(Hb, rowptr, cv, dinv, b2, P, partial, N, nbg);
    k_bnred<<<D, 256, 0, stream>>>(partial, nbg, g2, be2, ss2, invN);

    // ---- layer 3 (BN2+ReLU fused into gemm; final BN applied explicitly) ----
    k_gemm<1><<<ggrid, 256, 0, stream>>>(P, Wt3, Hb, N, ss2);
    k_gather<<<nbg, 256, 0, stream>>>(Hb, rowptr, cv, dinv, b3, P, partial, N, nbg);
    k_bnred<<<D, 256, 0, stream>>>(partial, nbg, g3, be3, ss3, invN);
    k_bnapply<<<pgrid, 256, 0, stream>>>(P, ss3, P, N);
}

// Round 8
// 435.543 us; speedup vs baseline: 2.3142x; 1.0940x over previous
//
#include <hip/hip_runtime.h>

#define D 128
#define BN_EPS 1e-5f
#define STILE 2048
#define NBG 2048                   // gather grid blocks

typedef unsigned short u16;
typedef unsigned long long u64;
typedef __attribute__((ext_vector_type(8))) short bf16x8;
typedef __attribute__((ext_vector_type(4))) float f32x4;

#define FIX_SCALE 1073741824.0f          // 2^30
#define FIX_INV   (1.0f / 1073741824.0f)
#define CNT_SHIFT 42
#define W_MASK    ((1ULL << CNT_SHIFT) - 1)

__device__ __forceinline__ float bf2f(u16 u) {
    unsigned v = (unsigned)u << 16; float f; __builtin_memcpy(&f, &v, 4); return f;
}
__device__ __forceinline__ u16 f2bf(float f) {
    unsigned v; __builtin_memcpy(&v, &f, 4);
    v += 0x7FFFu + ((v >> 16) & 1u);          // round-to-nearest-even
    return (u16)(v >> 16);
}

// ---------------- fused: W^T->bf16 (x3) + zero deg2 ----------------
__global__ __launch_bounds__(256) void k_wtz(const float* __restrict__ W1, const float* __restrict__ W2,
                                             const float* __restrict__ W3, u16* __restrict__ Wt1,
                                             u16* __restrict__ Wt2, u16* __restrict__ Wt3,
                                             int* __restrict__ zp, int nz)
{
    int bid = blockIdx.x;
    if (bid < 192) {
        int w = bid >> 6;
        int i = (bid & 63) * 256 + threadIdx.x;     // i = k*128 + c
        int k = i >> 7, c = i & 127;
        const float* W = w == 0 ? W1 : (w == 1 ? W2 : W3);
        u16* Wt = w == 0 ? Wt1 : (w == 1 ? Wt2 : Wt3);
        Wt[c * D + k] = f2bf(W[i]);
    } else {
        int i = (bid - 192) * 256 + threadIdx.x;
        if (i < nz) zp[i] = 0;
    }
}

// ---------------- GEMM body: H[N,128](bf16) = f(X) @ W ----------------
template <int FUSE_BN, int INB>
__device__ __forceinline__ void gemm_body(const void* __restrict__ Xv, const u16* __restrict__ Wt,
                                          u16* __restrict__ H, int N, const float* __restrict__ ss, int bid)
{
    int tid = threadIdx.x;
    int wv = tid >> 6, lane = tid & 63;
    int colA = lane & 15, oct = lane >> 4;
    int r0 = bid * 64;
    int c0 = wv * 32;

    bf16x8 bfr[2][4];
#pragma unroll
    for (int t = 0; t < 2; ++t)
#pragma unroll
        for (int kk = 0; kk < 4; ++kk)
            bfr[t][kk] = *(const bf16x8*)(Wt + (size_t)(c0 + t * 16 + colA) * D + kk * 32 + oct * 8);

    float4 sc[8], sh[8];
    if (FUSE_BN) {
#pragma unroll
        for (int kk = 0; kk < 4; ++kk) {
            sc[kk * 2 + 0] = *(const float4*)(ss + kk * 32 + oct * 8);
            sc[kk * 2 + 1] = *(const float4*)(ss + kk * 32 + oct * 8 + 4);
            sh[kk * 2 + 0] = *(const float4*)(ss + D + kk * 32 + oct * 8);
            sh[kk * 2 + 1] = *(const float4*)(ss + D + kk * 32 + oct * 8 + 4);
        }
    }

    for (int rs = 0; rs < 4; ++rs) {
        int r = r0 + rs * 16;
        int rr = r + colA; rr = rr < N ? rr : N - 1;          // clamp loads; stores guarded
        f32x4 acc0 = {0.f, 0.f, 0.f, 0.f}, acc1 = {0.f, 0.f, 0.f, 0.f};
#pragma unroll
        for (int kk = 0; kk < 4; ++kk) {
            bf16x8 a;
            if (!INB) {
                const float* xrow = (const float*)Xv + (size_t)rr * D + oct * 8;
                float4 xa = *(const float4*)(xrow + kk * 32);
                float4 xb = *(const float4*)(xrow + kk * 32 + 4);
                if (FUSE_BN) {
                    float4 s0 = sc[kk * 2], s1 = sc[kk * 2 + 1];
                    float4 h0 = sh[kk * 2], h1 = sh[kk * 2 + 1];
                    xa.x = fmaxf(fmaf(xa.x, s0.x, h0.x), 0.f);
                    xa.y = fmaxf(fmaf(xa.y, s0.y, h0.y), 0.f);
                    xa.z = fmaxf(fmaf(xa.z, s0.z, h0.z), 0.f);
                    xa.w = fmaxf(fmaf(xa.w, s0.w, h0.w), 0.f);
                    xb.x = fmaxf(fmaf(xb.x, s1.x, h1.x), 0.f);
                    xb.y = fmaxf(fmaf(xb.y, s1.y, h1.y), 0.f);
                    xb.z = fmaxf(fmaf(xb.z, s1.z, h1.z), 0.f);
                    xb.w = fmaxf(fmaf(xb.w, s1.w, h1.w), 0.f);
                }
                a[0] = (short)f2bf(xa.x); a[1] = (short)f2bf(xa.y);
                a[2] = (short)f2bf(xa.z); a[3] = (short)f2bf(xa.w);
                a[4] = (short)f2bf(xb.x); a[5] = (short)f2bf(xb.y);
                a[6] = (short)f2bf(xb.z); a[7] = (short)f2bf(xb.w);
            } else {
                const u16* brow = (const u16*)Xv + (size_t)rr * D + oct * 8;
                bf16x8 v = *(const bf16x8*)(brow + kk * 32);
                if (FUSE_BN) {
                    float4 s0 = sc[kk * 2], s1 = sc[kk * 2 + 1];
                    float4 h0 = sh[kk * 2], h1 = sh[kk * 2 + 1];
                    a[0] = (short)f2bf(fmaxf(fmaf(bf2f((u16)v[0]), s0.x, h0.x), 0.f));
                    a[1] = (short)f2bf(fmaxf(fmaf(bf2f((u16)v[1]), s0.y, h0.y), 0.f));
                    a[2] = (short)f2bf(fmaxf(fmaf(bf2f((u16)v[2]), s0.z, h0.z), 0.f));
                    a[3] = (short)f2bf(fmaxf(fmaf(bf2f((u16)v[3]), s0.w, h0.w), 0.f));
                    a[4] = (short)f2bf(fmaxf(fmaf(bf2f((u16)v[4]), s1.x, h1.x), 0.f));
                    a[5] = (short)f2bf(fmaxf(fmaf(bf2f((u16)v[5]), s1.y, h1.y), 0.f));
                    a[6] = (short)f2bf(fmaxf(fmaf(bf2f((u16)v[6]), s1.z, h1.z), 0.f));
                    a[7] = (short)f2bf(fmaxf(fmaf(bf2f((u16)v[7]), s1.w, h1.w), 0.f));
                } else {
                    a = v;
                }
            }
            acc0 = __builtin_amdgcn_mfma_f32_16x16x32_bf16(a, bfr[0][kk], acc0, 0, 0, 0);
            acc1 = __builtin_amdgcn_mfma_f32_16x16x32_bf16(a, bfr[1][kk], acc1, 0, 0, 0);
        }
        int orow = r + oct * 4;
        size_t obase = (size_t)orow * D + c0 + colA;
#pragma unroll
        for (int j = 0; j < 4; ++j) {
            if (orow + j < N) {
                H[obase + (size_t)j * D]      = f2bf(acc0[j]);
                H[obase + (size_t)j * D + 16] = f2bf(acc1[j]);
            }
        }
    }
}

// ---------------- fat kernel: gemm0 (blocks < ggrid) || k_deg (rest) ----------------
__global__ __launch_bounds__(256) void k_fat0(const float* __restrict__ X, const u16* __restrict__ Wt,
                                              u16* __restrict__ H, int N,
                                              const int* __restrict__ ei, const float* __restrict__ ew,
                                              u64* __restrict__ deg2, int* __restrict__ slot, int E, int ggrid)
{
    int bid = blockIdx.x;
    if (bid < ggrid) {
        gemm_body<0, 0>(X, Wt, H, N, nullptr, bid);
    } else {
        int e = (bid - ggrid) * 256 + threadIdx.x;
        if (e >= E) return;
        int d = ei[(size_t)E + e];
        u64 pk = (1ULL << CNT_SHIFT) | (u64)(ew[e] * FIX_SCALE + 0.5f);
        u64 old = atomicAdd(&deg2[d], pk);
        slot[e] = (int)(old >> CNT_SHIFT);
    }
}

// standalone gemm for layers 2,3 (bf16 in, BN+ReLU fused)
template <int FUSE_BN, int INB>
__global__ __launch_bounds__(256) void k_gemm(const void* __restrict__ Xv, const u16* __restrict__ Wt,
                                              u16* __restrict__ H, int N, const float* __restrict__ ss)
{
    gemm_body<FUSE_BN, INB>(Xv, Wt, H, N, ss, blockIdx.x);
}

// ---------------- scan1 (fused dinv) ----------------
__global__ __launch_bounds__(256) void k_scan1(const u64* __restrict__ deg2, float* __restrict__ dinv,
                                               int* __restrict__ rowptr, int* __restrict__ bsum, int N)
{
    __shared__ int wsum[4];
    int tid = threadIdx.x, lane = tid & 63, wid = tid >> 6;
    int i0 = blockIdx.x * STILE + tid * 8;
    int v[8]; int run = 0;
#pragma unroll
    for (int j = 0; j < 8; ++j) {
        int i = i0 + j;
        if (i < N) {
            u64 pv = deg2[i];
            v[j] = (int)(pv >> CNT_SHIFT);
            float wdeg = (float)(pv & W_MASK) * FIX_INV;
            dinv[i] = rsqrtf(wdeg + 1.0f);    // +1 = self-loop weight
        } else v[j] = 0;
        run += v[j];
    }
    int inc = run;
#pragma unroll
    for (int off = 1; off < 64; off <<= 1) {
        int t = __shfl_up(inc, (unsigned)off, 64);
        if (lane >= off) inc += t;
    }
    if (lane == 63) wsum[wid] = inc;
    __syncthreads();
    int woff = 0;
#pragma unroll
    for (int w = 0; w < 4; ++w) woff += (w < wid) ? wsum[w] : 0;
    int toff = woff + inc - run;
    int s = 0;
#pragma unroll
    for (int j = 0; j < 8; ++j) {
        int i = i0 + j;
        if (i < N) rowptr[i] = toff + s;
        s += v[j];
    }
    if (tid == 255) bsum[blockIdx.x] = woff + inc;
}

__global__ __launch_bounds__(64) void k_scan2(int* __restrict__ bsum, int* __restrict__ rowptrN, int nb)
{
    int lane = threadIdx.x;
    int carry = 0;
    for (int base = 0; base < nb; base += 64) {
        int i = base + lane;
        int v = (i < nb) ? bsum[i] : 0;
        int inc = v;
#pragma unroll
        for (int off = 1; off < 64; off <<= 1) {
            int t = __shfl_up(inc, (unsigned)off, 64);
            if (lane >= off) inc += t;
        }
        if (i < nb) bsum[i] = carry + inc - v;
        carry += __shfl(inc, 63, 64);
    }
    if (lane == 0) *rowptrN = carry;
}

__global__ __launch_bounds__(256) void k_scan3(int* __restrict__ rowptr, const int* __restrict__ bsum, int N)
{
    int i = blockIdx.x * 256 + threadIdx.x;
    if (i < N) rowptr[i] += bsum[i >> 11];
}

// fill CSR: no atomics
__global__ __launch_bounds__(256) void k_fill(const int* __restrict__ ei, const float* __restrict__ ew,
                                              const float* __restrict__ dinv, const int* __restrict__ rowptr,
                                              const int* __restrict__ slot, int2* __restrict__ cv, int E)
{
    int e = blockIdx.x * 256 + threadIdx.x;
    if (e >= E) return;
    int s = ei[e];
    int d = ei[(size_t)E + e];
    float nrm = dinv[s] * ew[e] * dinv[d];
    int p = rowptr[d] + slot[e];
    cv[p] = make_int2(s, __float_as_int(nrm));
}

// ---------------- aggregation + fused BN partial stats ----------------
template <int OUTB>
__global__ __launch_bounds__(256) void k_gather(const u16* __restrict__ h, const int* __restrict__ rowptr,
                                                const int2* __restrict__ cv, const float* __restrict__ dinv,
                                                const float* __restrict__ bias, u16* __restrict__ outb,
                                                float* __restrict__ outf, float* __restrict__ partial,
                                                int N, int nbg)
{
    int lane = threadIdx.x & 63, wv = threadIdx.x >> 6;
    float2 b = ((const float2*)bias)[lane];
    float4 st = {0.f, 0.f, 0.f, 0.f};
    for (int wid = blockIdx.x * 4 + wv; wid < N; wid += nbg * 4) {
        float di = dinv[wid];
        float sw = di * di;
        ushort2 hv = ((const ushort2*)(h + (size_t)wid * D))[lane];
        float ax = bf2f(hv.x) * sw, ay = bf2f(hv.y) * sw;
        int j   = __builtin_amdgcn_readfirstlane(rowptr[wid]);
        int end = __builtin_amdgcn_readfirstlane(rowptr[wid + 1]);
        for (; j + 4 <= end; j += 4) {
            int2 e0 = cv[j], e1 = cv[j + 1], e2 = cv[j + 2], e3 = cv[j + 3];
            float w0 = __int_as_float(e0.y), w1 = __int_as_float(e1.y);
            float w2 = __int_as_float(e2.y), w3 = __int_as_float(e3.y);
            ushort2 v0 = ((const ushort2*)(h + (size_t)e0.x * D))[lane];
            ushort2 v1 = ((const ushort2*)(h + (size_t)e1.x * D))[lane];
            ushort2 v2 = ((const ushort2*)(h + (size_t)e2.x * D))[lane];
            ushort2 v3 = ((const ushort2*)(h + (size_t)e3.x * D))[lane];
            ax = fmaf(w0, bf2f(v0.x), ax); ay = fmaf(w0, bf2f(v0.y), ay);
            ax = fmaf(w1, bf2f(v1.x), ax); ay = fmaf(w1, bf2f(v1.y), ay);
            ax = fmaf(w2, bf2f(v2.x), ax); ay = fmaf(w2, bf2f(v2.y), ay);
            ax = fmaf(w3, bf2f(v3.x), ax); ay = fmaf(w3, bf2f(v3.y), ay);
        }
        for (; j < end; ++j) {
            int2 e0 = cv[j];
            float w0 = __int_as_float(e0.y);
            ushort2 v0 = ((const ushort2*)(h + (size_t)e0.x * D))[lane];
            ax = fmaf(w0, bf2f(v0.x), ax); ay = fmaf(w0, bf2f(v0.y), ay);
        }
        float ox = ax + b.x, oy = ay + b.y;
        if (OUTB) {
            ushort2 ob; ob.x = f2bf(ox); ob.y = f2bf(oy);
            ((ushort2*)(outb + (size_t)wid * D))[lane] = ob;
        } else {
            float2 o; o.x = ox; o.y = oy;
            ((float2*)(outf + (size_t)wid * D))[lane] = o;
        }
        st.x += ox; st.y = fmaf(ox, ox, st.y);
        st.z += oy; st.w = fmaf(oy, oy, st.w);
    }
    __shared__ float4 red[4][64];
    red[wv][lane] = st;
    __syncthreads();
    if (wv == 0) {
        float4 a0 = red[0][lane], a1 = red[1][lane], a2 = red[2][lane], a3 = red[3][lane];
        float4 t;
        t.x = a0.x + a1.x + a2.x + a3.x;
        t.y = a0.y + a1.y + a2.y + a3.y;
        t.z = a0.z + a1.z + a2.z + a3.z;
        t.w = a0.w + a1.w + a2.w + a3.w;
        ((float4*)partial)[(size_t)blockIdx.x * 64 + lane] = t;
    }
}

// ---------------- reduce partials -> BN scale/shift ----------------
__global__ __launch_bounds__(256) void k_bnred(const float* __restrict__ partial, int nbg,
                                               const float* __restrict__ g, const float* __restrict__ be,
                                               float* __restrict__ ss, float invN)
{
    int c = blockIdx.x;
    int q = (c >> 1) * 4 + ((c & 1) << 1);
    int t = threadIdx.x;
    float s = 0.f, s2 = 0.f;
    for (int bb = t; bb < nbg; bb += 256) {
        const float* row = partial + (size_t)bb * 256 + q;
        s += row[0]; s2 += row[1];
    }
#pragma unroll
    for (int off = 32; off; off >>= 1) {
        s  += __shfl_down(s,  (unsigned)off, 64);
        s2 += __shfl_down(s2, (unsigned)off, 64);
    }
    __shared__ float rs_[4], rq_[4];
    int wv = t >> 6, lane = t & 63;
    if (lane == 0) { rs_[wv] = s; rq_[wv] = s2; }
    __syncthreads();
    if (t == 0) {
        float S = rs_[0] + rs_[1] + rs_[2] + rs_[3];
        float Q = rq_[0] + rq_[1] + rq_[2] + rq_[3];
        float mu = S * invN;
        float var = fmaxf(Q * invN - mu * mu, 0.f);
        float r = rsqrtf(var + BN_EPS);
        float sc = r * g[c];
        ss[c] = sc;
        ss[D + c] = be[c] - mu * sc;
    }
}

// final BN apply: y = x*sc + sh
__global__ __launch_bounds__(256) void k_bnapply(const float* __restrict__ in, const float* __restrict__ ss,
                                                 float* __restrict__ out, int N)
{
    int idx = blockIdx.x * 256 + threadIdx.x;
    if (idx >= N * 32) return;
    int cc = idx & 31;
    float4 xv = ((const float4*)in)[idx];
    float4 sc = ((const float4*)ss)[cc];
    float4 sh = ((const float4*)(ss + D))[cc];
    float4 o;
    o.x = fmaf(xv.x, sc.x, sh.x);
    o.y = fmaf(xv.y, sc.y, sh.y);
    o.z = fmaf(xv.z, sc.z, sh.z);
    o.w = fmaf(xv.w, sc.w, sh.w);
    ((float4*)out)[idx] = o;
}

// ---------------- launch ----------------
extern "C" void kernel_launch(void* const* d_in, const int* in_sizes, int n_in,
                              void* d_out, int out_size, void* d_ws, size_t ws_size,
                              hipStream_t stream)
{
    const float* x  = (const float*)d_in[0];
    const int*   ei = (const int*)d_in[1];      // int32 on device
    const float* ew = (const float*)d_in[2];
    const float* W1 = (const float*)d_in[4];
    const float* b1 = (const float*)d_in[5];
    const float* W2 = (const float*)d_in[6];
    const float* b2 = (const float*)d_in[7];
    const float* W3 = (const float*)d_in[8];
    const float* b3 = (const float*)d_in[9];
    const float* g1 = (const float*)d_in[10];
    const float* be1 = (const float*)d_in[11];
    const float* g2 = (const float*)d_in[12];
    const float* be2 = (const float*)d_in[13];
    const float* g3 = (const float*)d_in[14];
    const float* be3 = (const float*)d_in[15];

    int N = in_sizes[0] / D;
    int E = in_sizes[1] / 2;
    float* P  = (float*)d_out;                       // final f32 activations / output
    u16*   Pb = (u16*)d_out;                         // bf16 inter-layer activations (first 25.6MB)
    int*   slot = (int*)((char*)d_out + ((size_t)32 << 20));  // d_out[32MB..38.4MB): dead until gather3

    char* ws = (char*)d_ws;
    size_t off = 0;
    auto alloc = [&](size_t bytes) -> void* {
        void* p = ws + off;
        off = (off + bytes + 255) & ~(size_t)255;
        return p;
    };
    u16*   Hb    = (u16*)alloc((size_t)N * D * 2);      // bf16 GEMM output
    float* dinv  = (float*)alloc((size_t)N * 4);
    int*   rowptr= (int*)alloc((size_t)(N + 1) * 4);
    int2*  cv    = (int2*)alloc((size_t)E * 8);         // (col, nrm); deg2 overlays
    float* partial = (float*)alloc((size_t)NBG * 256 * 4);
    int*   bsum  = (int*)alloc(((size_t)(N / STILE) + 2) * 4);
    float* ss1   = (float*)alloc(1024);
    float* ss2   = (float*)alloc(1024);
    float* ss3   = (float*)alloc(1024);
    u16*   Wt1   = (u16*)alloc((size_t)D * D * 2);
    u16*   Wt2   = (u16*)alloc((size_t)D * D * 2);
    u16*   Wt3   = (u16*)alloc((size_t)D * D * 2);
    u64*   deg2  = (u64*)cv;       // overlay: dies after scan1, before fill writes cv

    float invN = 1.0f / (float)N;
    int egrid = (E + 255) / 256;
    int ggrid = (N + 63) / 64;
    int pgrid = (N * 32 + 255) / 256;
    int nb    = (N + STILE - 1) / STILE;
    int nbg   = NBG < (N + 3) / 4 ? NBG : (N + 3) / 4;
    int nz    = N * 2;                                 // deg2 zero extent in ints
    int zgrid = (nz + 255) / 256;

    // ---- weights + zero (fused), then gemm0 || deg (fat), then CSR ----
    k_wtz<<<192 + zgrid, 256, 0, stream>>>(W1, W2, W3, Wt1, Wt2, Wt3, (int*)deg2, nz);
    k_fat0<<<ggrid + egrid, 256, 0, stream>>>(x, Wt1, Hb, N, ei, ew, deg2, slot, E, ggrid);
    k_scan1<<<nb, 256, 0, stream>>>(deg2, dinv, rowptr, bsum, N);
    k_scan2<<<1, 64, 0, stream>>>(bsum, rowptr + N, nb);
    k_scan3<<<(N + 255) / 256, 256, 0, stream>>>(rowptr, bsum, N);
    k_fill<<<egrid, 256, 0, stream>>>(ei, ew, dinv, rowptr, slot, cv, E);

    // ---- layer 1 ----
    k_gather<1><<<nbg, 256, 0, stream>>>(Hb, rowptr, cv, dinv, b1, Pb, nullptr, partial, N, nbg);
    k_bnred<<<D, 256, 0, stream>>>(partial, nbg, g1, be1, ss1, invN);

    // ---- layer 2 (BN1+ReLU fused into gemm, bf16 in) ----
    k_gemm<1, 1><<<ggrid, 256, 0, stream>>>(Pb, Wt2, Hb, N, ss1);
    k_gather<1><<<nbg, 256, 0, stream>>>(Hb, rowptr, cv, dinv, b2, Pb, nullptr, partial, N, nbg);
    k_bnred<<<D, 256, 0, stream>>>(partial, nbg, g2, be2, ss2, invN);

    // ---- layer 3 (BN2+ReLU fused into gemm; final BN explicit) ----
    k_gemm<1, 1><<<ggrid, 256, 0, stream>>>(Pb, Wt3, Hb, N, ss2);
    k_gather<0><<<nbg, 256, 0, stream>>>(Hb, rowptr, cv, dinv, b3, nullptr, P, partial, N, nbg);
    k_bnred<<<D, 256, 0, stream>>>(partial, nbg, g3, be3, ss3, invN);
    k_bnapply<<<pgrid, 256, 0, stream>>>(P, ss3, P, N);
}